// Round 2
// baseline (2665.237 us; speedup 1.0000x reference)
//
#include <hip/hip_runtime.h>
#include <math.h>
#include <stdint.h>

#define KP 16384
#define IN_DIM 512
#define HD 1024

// ---------------- threefry2x32 (JAX key(42) => k0=0, k1=42) ----------------
__device__ __forceinline__ uint32_t rotl(uint32_t x, uint32_t r) {
  return (x << r) | (x >> (32u - r));
}

__device__ __forceinline__ void threefry2x32(uint32_t x0, uint32_t x1,
                                             uint32_t& o0, uint32_t& o1) {
  const uint32_t ks0 = 0u, ks1 = 42u, ks2 = 0u ^ 42u ^ 0x1BD11BDAu;
  x0 += ks0; x1 += ks1;
#define TF_R4(r0, r1, r2, r3) \
  x0 += x1; x1 = rotl(x1, r0); x1 ^= x0; \
  x0 += x1; x1 = rotl(x1, r1); x1 ^= x0; \
  x0 += x1; x1 = rotl(x1, r2); x1 ^= x0; \
  x0 += x1; x1 = rotl(x1, r3); x1 ^= x0;
  TF_R4(13u,15u,26u,6u);   x0 += ks1; x1 += ks2 + 1u;
  TF_R4(17u,29u,16u,24u);  x0 += ks2; x1 += ks0 + 2u;
  TF_R4(13u,15u,26u,6u);   x0 += ks0; x1 += ks1 + 3u;
  TF_R4(17u,29u,16u,24u);  x0 += ks1; x1 += ks2 + 4u;
  TF_R4(13u,15u,26u,6u);   x0 += ks2; x1 += ks0 + 5u;
#undef TF_R4
  o0 = x0; o1 = x1;
}

// JAX uniform(minval=tiny, maxval=1) bits->float, then gumbel = -log(-log(u))
__device__ __forceinline__ float gumbel_from_bits(uint32_t b) {
  uint32_t ub = (b >> 9) | 0x3f800000u;
  float u = __uint_as_float(ub) - 1.0f;
  u = fmaxf(u, 1.1754943508222875e-38f);
  return -logf(-logf(u));
}

// ---------------- bias precompute: input_ @ W[1024:,:] + b ----------------
__global__ __launch_bounds__(256) void bias_kernel(
    const float* __restrict__ in,
    const float* __restrict__ wz, const float* __restrict__ bz,
    const float* __restrict__ wr, const float* __restrict__ br,
    const float* __restrict__ wn, const float* __restrict__ bn,
    const float* __restrict__ wobs, const float* __restrict__ bobs,
    float* __restrict__ zb, float* __restrict__ rb,
    float* __restrict__ nb, float* __restrict__ ob) {
  __shared__ float sin_[IN_DIM];
  int t = threadIdx.x;
  for (int i = t; i < IN_DIM; i += 256) sin_[i] = in[i];
  __syncthreads();
  int gid = blockIdx.x * 256 + t;
  if (gid < 1024) {
    float s = bz[gid];
    for (int i = 0; i < IN_DIM; ++i) s = fmaf(sin_[i], wz[(HD + i) * HD + gid], s);
    zb[gid] = s;
  } else if (gid < 2048) {
    int j = gid - 1024;
    float s = br[j];
    for (int i = 0; i < IN_DIM; ++i) s = fmaf(sin_[i], wr[(HD + i) * HD + j], s);
    rb[j] = s;
  } else if (gid < 4096) {
    int j = gid - 2048;
    float s = bn[j];
    for (int i = 0; i < IN_DIM; ++i) s = fmaf(sin_[i], wn[(HD + i) * 2048 + j], s);
    nb[j] = s;
  } else if (gid == 4096) {
    float s = bobs[0];
    for (int i = 0; i < IN_DIM; ++i) s = fmaf(sin_[i], wobs[HD + i], s);
    ob[0] = s;
  }
}

// ---------------- GEMM: z = sigmoid(h0@Wz+zb), rh = sigmoid(h0@Wr+rb)*h0 ----
#define BM 128
#define BN 64
#define BK 32

__global__ __launch_bounds__(256) void gemm_zr_kernel(
    const float* __restrict__ A,    // h0: KP x HD
    const float* __restrict__ Wz,   // 1536 x 1024 (rows 0..1023 used)
    const float* __restrict__ Wr,
    const float* __restrict__ zbias, const float* __restrict__ rbias,
    float* __restrict__ zout,       // KP x HD
    float* __restrict__ rhout) {    // KP x HD
  __shared__ float As[BK][BM + 1];
  __shared__ float Bzs[BK][BN + 1];
  __shared__ float Brs[BK][BN + 1];
  int t = threadIdx.x;
  int tx = t & 15, ty = t >> 4;
  int row0 = blockIdx.x * BM, col0 = blockIdx.y * BN;

  float acc_z[8][4] = {};
  float acc_r[8][4] = {};

  for (int kb = 0; kb < HD; kb += BK) {
#pragma unroll
    for (int p = 0; p < 4; ++p) {
      int r = (t >> 3) + p * 32;
      int q = (t & 7) * 4;
      float4 v = *(const float4*)&A[(size_t)(row0 + r) * HD + kb + q];
      As[q + 0][r] = v.x; As[q + 1][r] = v.y; As[q + 2][r] = v.z; As[q + 3][r] = v.w;
    }
#pragma unroll
    for (int p = 0; p < 2; ++p) {
      int r = (t >> 4) + p * 16;
      int q = (t & 15) * 4;
      *(float4*)&Bzs[r][q] = *(const float4*)&Wz[(size_t)(kb + r) * HD + col0 + q];
      *(float4*)&Brs[r][q] = *(const float4*)&Wr[(size_t)(kb + r) * HD + col0 + q];
    }
    __syncthreads();
#pragma unroll 4
    for (int kk = 0; kk < BK; ++kk) {
      float a[8], bz4[4], br4[4];
#pragma unroll
      for (int i = 0; i < 8; ++i) a[i] = As[kk][ty * 8 + i];
#pragma unroll
      for (int j = 0; j < 4; ++j) { bz4[j] = Bzs[kk][tx * 4 + j]; br4[j] = Brs[kk][tx * 4 + j]; }
#pragma unroll
      for (int i = 0; i < 8; ++i)
#pragma unroll
        for (int j = 0; j < 4; ++j) {
          acc_z[i][j] = fmaf(a[i], bz4[j], acc_z[i][j]);
          acc_r[i][j] = fmaf(a[i], br4[j], acc_r[i][j]);
        }
    }
    __syncthreads();
  }
#pragma unroll
  for (int i = 0; i < 8; ++i) {
    int row = row0 + ty * 8 + i;
    float4 h4 = *(const float4*)&A[(size_t)row * HD + col0 + tx * 4];
    float h[4] = {h4.x, h4.y, h4.z, h4.w};
#pragma unroll
    for (int j = 0; j < 4; ++j) {
      int col = col0 + tx * 4 + j;
      float z = 1.0f / (1.0f + expf(-(acc_z[i][j] + zbias[col])));
      float r = 1.0f / (1.0f + expf(-(acc_r[i][j] + rbias[col])));
      zout[(size_t)row * HD + col] = z;
      rhout[(size_t)row * HD + col] = r * h[j];
    }
  }
}

// ---------------- GEMM: n_pre = rh@Wn[:1024] + nb; fused h1 epilogue --------
__global__ __launch_bounds__(256) void gemm_n_kernel(
    const float* __restrict__ A,     // rh: KP x HD
    const float* __restrict__ Wn,    // 1536 x 2048 (rows 0..1023 used)
    const float* __restrict__ nbias, // 2048
    const float* __restrict__ h0,
    const float* __restrict__ eps,
    const float* __restrict__ zbuf,  // z: KP x HD
    float* __restrict__ h1out) {     // KP x HD
  __shared__ float As[BK][BM + 1];
  __shared__ float Bms[BK][BN + 1];
  __shared__ float Bvs[BK][BN + 1];
  int t = threadIdx.x;
  int tx = t & 15, ty = t >> 4;
  int row0 = blockIdx.x * BM, col0 = blockIdx.y * BN;

  float acc_m[8][4] = {};
  float acc_v[8][4] = {};

  for (int kb = 0; kb < HD; kb += BK) {
#pragma unroll
    for (int p = 0; p < 4; ++p) {
      int r = (t >> 3) + p * 32;
      int q = (t & 7) * 4;
      float4 v = *(const float4*)&A[(size_t)(row0 + r) * HD + kb + q];
      As[q + 0][r] = v.x; As[q + 1][r] = v.y; As[q + 2][r] = v.z; As[q + 3][r] = v.w;
    }
#pragma unroll
    for (int p = 0; p < 2; ++p) {
      int r = (t >> 4) + p * 16;
      int q = (t & 15) * 4;
      *(float4*)&Bms[r][q] = *(const float4*)&Wn[(size_t)(kb + r) * 2048 + col0 + q];
      *(float4*)&Bvs[r][q] = *(const float4*)&Wn[(size_t)(kb + r) * 2048 + 1024 + col0 + q];
    }
    __syncthreads();
#pragma unroll 4
    for (int kk = 0; kk < BK; ++kk) {
      float a[8], bm[4], bv[4];
#pragma unroll
      for (int i = 0; i < 8; ++i) a[i] = As[kk][ty * 8 + i];
#pragma unroll
      for (int j = 0; j < 4; ++j) { bm[j] = Bms[kk][tx * 4 + j]; bv[j] = Bvs[kk][tx * 4 + j]; }
#pragma unroll
      for (int i = 0; i < 8; ++i)
#pragma unroll
        for (int j = 0; j < 4; ++j) {
          acc_m[i][j] = fmaf(a[i], bm[j], acc_m[i][j]);
          acc_v[i][j] = fmaf(a[i], bv[j], acc_v[i][j]);
        }
    }
    __syncthreads();
  }
#pragma unroll
  for (int i = 0; i < 8; ++i) {
    int row = row0 + ty * 8 + i;
    float4 h4 = *(const float4*)&h0[(size_t)row * HD + col0 + tx * 4];
    float4 e4 = *(const float4*)&eps[(size_t)row * HD + col0 + tx * 4];
    float hv[4] = {h4.x, h4.y, h4.z, h4.w};
    float ev[4] = {e4.x, e4.y, e4.z, e4.w};
#pragma unroll
    for (int j = 0; j < 4; ++j) {
      int col = col0 + tx * 4 + j;
      float mu = acc_m[i][j] + nbias[col];
      float var = acc_v[i][j] + nbias[1024 + col];
      float sp = fmaxf(var, 0.0f) + log1pf(expf(-fabsf(var)));
      float n = tanhf(mu + ev[j] * sp);
      float z = zbuf[(size_t)row * HD + col];
      h1out[(size_t)row * HD + col] = (1.0f - z) * n + z * hv[j];
    }
  }
}

// ---------------- score: s = h1@wobs[:1024] + ob + p0 ----------------------
__global__ __launch_bounds__(256) void score_kernel(
    const float* __restrict__ h1, const float* __restrict__ wobs,
    const float* __restrict__ ob, const float* __restrict__ p0,
    float* __restrict__ s) {
  __shared__ float w[HD];
  int t = threadIdx.x;
  for (int i = t; i < HD; i += 256) w[i] = wobs[i];
  __syncthreads();
  int wave = t >> 6, lane = t & 63;
  int row = blockIdx.x * 4 + wave;
  float acc = 0.0f;
  for (int c = lane * 4; c < HD; c += 256) {
    float4 v = *(const float4*)&h1[(size_t)row * HD + c];
    acc = fmaf(v.x, w[c], acc);
    acc = fmaf(v.y, w[c + 1], acc);
    acc = fmaf(v.z, w[c + 2], acc);
    acc = fmaf(v.w, w[c + 3], acc);
  }
#pragma unroll
  for (int off = 32; off; off >>= 1) acc += __shfl_down(acc, off);
  if (lane == 0) s[row] = acc + ob[0] + p0[row];
}

// ---------------- log_softmax over K + categorical logits ------------------
__global__ __launch_bounds__(1024) void softmax_kernel(
    const float* __restrict__ s, float* __restrict__ p1v, float* __restrict__ logits) {
  __shared__ float red[1024];
  int t = threadIdx.x;
  float m = -INFINITY;
  for (int k = t; k < KP; k += 1024) m = fmaxf(m, s[k]);
  red[t] = m; __syncthreads();
  for (int o = 512; o; o >>= 1) { if (t < o) red[t] = fmaxf(red[t], red[t + o]); __syncthreads(); }
  m = red[0]; __syncthreads();
  float sum = 0.0f;
  for (int k = t; k < KP; k += 1024) sum += expf(s[k] - m);
  red[t] = sum; __syncthreads();
  for (int o = 512; o; o >>= 1) { if (t < o) red[t] += red[t + o]; __syncthreads(); }
  float ls = logf(red[0]);
  for (int k = t; k < KP; k += 1024) {
    float p = s[k] - m - ls;
    p1v[k] = p;
    logits[k] = logf(0.5f * expf(p) + (0.5f / KP));
  }
}

// ---------------- categorical (partitionable threefry, default in JAX>=0.4.36)
// bits[i] = o0 ^ o1 of threefry2x32(key=(0,42), counts=(hi32(i)=0, lo32(i)=i))
// G[r,c] uses i = r*16384 + c; idx[r] = argmax_c(gumbel(bits[i]) + logits[c])
__global__ __launch_bounds__(256) void categorical_kernel(
    const float* __restrict__ logits, int* __restrict__ idx) {
  __shared__ float sv[256];
  __shared__ int si[256];
  int r = blockIdx.x;  // 0..16383
  int t = threadIdx.x;
  float best = -INFINITY;
  int bi = 0;
  uint32_t base = (uint32_t)r << 14;
  for (int c = t; c < KP; c += 256) {
    uint32_t o0, o1;
    threefry2x32(0u, base | (uint32_t)c, o0, o1);
    float g = gumbel_from_bits(o0 ^ o1) + logits[c];
    if (g > best) { best = g; bi = c; }
  }
  sv[t] = best; si[t] = bi; __syncthreads();
  for (int o = 128; o; o >>= 1) {
    if (t < o) {
      if (sv[t + o] > sv[t] || (sv[t + o] == sv[t] && si[t + o] < si[t])) {
        sv[t] = sv[t + o]; si[t] = si[t + o];
      }
    }
    __syncthreads();
  }
  if (t == 0) idx[r] = si[0];
}

// ---------------- resample weights + final p1 ------------------------------
__global__ __launch_bounds__(1024) void resample_kernel(
    const float* __restrict__ p1v, const int* __restrict__ idx,
    float* __restrict__ pn, float* __restrict__ p1out, float* __restrict__ wexp) {
  __shared__ float red[1024];
  int t = threadIdx.x;
  float m = -INFINITY;
  for (int k = t; k < KP; k += 1024) {
    float pv = p1v[idx[k]];
    float w = expf(pv);
    float v = logf(w / (0.5f * w + (0.5f / KP)));
    pn[k] = v;
    m = fmaxf(m, v);
  }
  red[t] = m; __syncthreads();
  for (int o = 512; o; o >>= 1) { if (t < o) red[t] = fmaxf(red[t], red[t + o]); __syncthreads(); }
  m = red[0]; __syncthreads();
  float sum = 0.0f;
  for (int k = t; k < KP; k += 1024) sum += expf(pn[k] - m);
  red[t] = sum; __syncthreads();
  for (int o = 512; o; o >>= 1) { if (t < o) red[t] += red[t + o]; __syncthreads(); }
  float lse = m + logf(red[0]);
  for (int k = t; k < KP; k += 1024) {
    float v = pn[k] - lse;
    p1out[k] = v;
    wexp[k] = expf(v);
  }
}

// ---------------- gather h1 + per-block partial weighted sums --------------
__global__ __launch_bounds__(256) void gather_kernel(
    const float* __restrict__ h1pre, const int* __restrict__ idx,
    const float* __restrict__ wexp, float* __restrict__ h1out,
    float* __restrict__ partials) {
  int t = threadIdx.x;
  int k0 = blockIdx.x * 64;
  float part[4] = {0.f, 0.f, 0.f, 0.f};
  for (int kk = 0; kk < 64; ++kk) {
    int k = k0 + kk;
    int src = idx[k];
    float w = wexp[k];
#pragma unroll
    for (int c = 0; c < 4; ++c) {
      float v = h1pre[(size_t)src * HD + t + c * 256];
      h1out[(size_t)k * HD + t + c * 256] = v;
      part[c] = fmaf(w, v, part[c]);
    }
  }
#pragma unroll
  for (int c = 0; c < 4; ++c) partials[(size_t)blockIdx.x * HD + t + c * 256] = part[c];
}

__global__ __launch_bounds__(256) void reduce_mean_kernel(
    const float* __restrict__ partials, float* __restrict__ mean_hid) {
  int j = blockIdx.x * 256 + threadIdx.x;
  float s = 0.0f;
  for (int b = 0; b < 256; ++b) s += partials[(size_t)b * HD + j];
  mean_hid[j] = s;
}

// ---------------- final 2-layer head ---------------------------------------
__global__ __launch_bounds__(64) void final_kernel(
    const float* __restrict__ mean_hid,
    const float* __restrict__ wh1, const float* __restrict__ bh1,
    const float* __restrict__ wh2, const float* __restrict__ bh2,
    float* __restrict__ out) {
  __shared__ float hrelu[24];
  int t = threadIdx.x;
  if (t < 24) {
    float s = bh1[t];
    for (int i = 0; i < HD; ++i) s = fmaf(mean_hid[i], wh1[i * 24 + t], s);
    hrelu[t] = fmaxf(s, 0.0f);
  }
  __syncthreads();
  if (t < 2) {
    float s = bh2[t];
    for (int j = 0; j < 24; ++j) s = fmaf(hrelu[j], wh2[j * 2 + t], s);
    out[t] = s;
  }
}

extern "C" void kernel_launch(void* const* d_in, const int* in_sizes, int n_in,
                              void* d_out, int out_size, void* d_ws, size_t ws_size,
                              hipStream_t stream) {
  (void)in_sizes; (void)n_in; (void)out_size; (void)ws_size;
  const float* input_ = (const float*)d_in[0];
  const float* h0    = (const float*)d_in[1];
  const float* p0    = (const float*)d_in[2];
  const float* eps   = (const float*)d_in[3];
  const float* w_z   = (const float*)d_in[4];
  const float* b_z   = (const float*)d_in[5];
  const float* w_r   = (const float*)d_in[6];
  const float* b_r   = (const float*)d_in[7];
  const float* w_n   = (const float*)d_in[8];
  const float* b_n   = (const float*)d_in[9];
  const float* w_obs = (const float*)d_in[10];
  const float* b_obs = (const float*)d_in[11];
  const float* w_h1  = (const float*)d_in[12];
  const float* b_h1  = (const float*)d_in[13];
  const float* w_h2  = (const float*)d_in[14];
  const float* b_h2  = (const float*)d_in[15];

  float* out = (float*)d_out;
  float* out_loc = out;                       // 2
  float* out_h1  = out + 2;                   // KP*HD  (also used as z scratch)
  float* out_p1  = out + 2 + (size_t)KP * HD; // KP

  float* ws = (float*)d_ws;
  float* rh      = ws;                          // KP*HD
  float* h1pre   = ws + (size_t)KP * HD;        // KP*HD
  float* zb      = ws + 2 * (size_t)KP * HD;    // 1024
  float* rb      = zb + 1024;                   // 1024
  float* nb      = rb + 1024;                   // 2048
  float* ob      = nb + 2048;                   // 1 (pad 16)
  float* sbuf    = ob + 16;                     // KP
  float* p1v     = sbuf + KP;                   // KP
  float* logits  = p1v + KP;                    // KP
  float* pn      = logits + KP;                 // KP
  float* wexpb   = pn + KP;                     // KP
  float* mean_hid= wexpb + KP;                  // 1024
  float* partials= mean_hid + 1024;             // 256*1024
  int*   idxb    = (int*)(partials + 256 * HD); // KP ints

  bias_kernel<<<17, 256, 0, stream>>>(input_, w_z, b_z, w_r, b_r, w_n, b_n,
                                      w_obs, b_obs, zb, rb, nb, ob);

  dim3 g1(KP / BM, HD / BN);
  gemm_zr_kernel<<<g1, 256, 0, stream>>>(h0, w_z, w_r, zb, rb, out_h1 /*z*/, rh);

  gemm_n_kernel<<<g1, 256, 0, stream>>>(rh, w_n, nb, h0, eps, out_h1 /*z*/, h1pre);

  score_kernel<<<KP / 4, 256, 0, stream>>>(h1pre, w_obs, ob, p0, sbuf);

  softmax_kernel<<<1, 1024, 0, stream>>>(sbuf, p1v, logits);

  categorical_kernel<<<KP, 256, 0, stream>>>(logits, idxb);

  resample_kernel<<<1, 1024, 0, stream>>>(p1v, idxb, pn, out_p1, wexpb);

  gather_kernel<<<KP / 64, 256, 0, stream>>>(h1pre, idxb, wexpb, out_h1, partials);

  reduce_mean_kernel<<<4, 256, 0, stream>>>(partials, mean_hid);

  final_kernel<<<1, 64, 0, stream>>>(mean_hid, w_h1, b_h1, w_h2, b_h2, out_loc);
}

// Round 3
// 2354.776 us; speedup vs baseline: 1.1318x; 1.1318x over previous
//
#include <hip/hip_runtime.h>
#include <math.h>
#include <stdint.h>

#define KP 16384
#define IN_DIM 512
#define HD 1024

// ---------------- threefry2x32 (JAX key(42) => k0=0, k1=42) ----------------
__device__ __forceinline__ uint32_t rotl(uint32_t x, uint32_t r) {
  return (x << r) | (x >> (32u - r));
}

__device__ __forceinline__ void threefry2x32(uint32_t x0, uint32_t x1,
                                             uint32_t& o0, uint32_t& o1) {
  const uint32_t ks0 = 0u, ks1 = 42u, ks2 = 0u ^ 42u ^ 0x1BD11BDAu;
  x0 += ks0; x1 += ks1;
#define TF_R4(r0, r1, r2, r3) \
  x0 += x1; x1 = rotl(x1, r0); x1 ^= x0; \
  x0 += x1; x1 = rotl(x1, r1); x1 ^= x0; \
  x0 += x1; x1 = rotl(x1, r2); x1 ^= x0; \
  x0 += x1; x1 = rotl(x1, r3); x1 ^= x0;
  TF_R4(13u,15u,26u,6u);   x0 += ks1; x1 += ks2 + 1u;
  TF_R4(17u,29u,16u,24u);  x0 += ks2; x1 += ks0 + 2u;
  TF_R4(13u,15u,26u,6u);   x0 += ks0; x1 += ks1 + 3u;
  TF_R4(17u,29u,16u,24u);  x0 += ks1; x1 += ks2 + 4u;
  TF_R4(13u,15u,26u,6u);   x0 += ks2; x1 += ks0 + 5u;
#undef TF_R4
  o0 = x0; o1 = x1;
}

// JAX uniform(minval=tiny, maxval=1) bits->float, then gumbel = -log(-log(u))
__device__ __forceinline__ float gumbel_from_bits(uint32_t b) {
  uint32_t ub = (b >> 9) | 0x3f800000u;
  float u = __uint_as_float(ub) - 1.0f;
  u = fmaxf(u, 1.1754943508222875e-38f);
  return -logf(-logf(u));
}

// ---------------- bias precompute: input_ @ W[1024:,:] + b ----------------
__global__ __launch_bounds__(256) void bias_kernel(
    const float* __restrict__ in,
    const float* __restrict__ wz, const float* __restrict__ bz,
    const float* __restrict__ wr, const float* __restrict__ br,
    const float* __restrict__ wn, const float* __restrict__ bn,
    const float* __restrict__ wobs, const float* __restrict__ bobs,
    float* __restrict__ zb, float* __restrict__ rb,
    float* __restrict__ nb, float* __restrict__ ob) {
  __shared__ float sin_[IN_DIM];
  int t = threadIdx.x;
  for (int i = t; i < IN_DIM; i += 256) sin_[i] = in[i];
  __syncthreads();
  int gid = blockIdx.x * 256 + t;
  if (gid < 1024) {
    float s = bz[gid];
    for (int i = 0; i < IN_DIM; ++i) s = fmaf(sin_[i], wz[(HD + i) * HD + gid], s);
    zb[gid] = s;
  } else if (gid < 2048) {
    int j = gid - 1024;
    float s = br[j];
    for (int i = 0; i < IN_DIM; ++i) s = fmaf(sin_[i], wr[(HD + i) * HD + j], s);
    rb[j] = s;
  } else if (gid < 4096) {
    int j = gid - 2048;
    float s = bn[j];
    for (int i = 0; i < IN_DIM; ++i) s = fmaf(sin_[i], wn[(HD + i) * 2048 + j], s);
    nb[j] = s;
  } else if (gid == 4096) {
    float s = bobs[0];
    for (int i = 0; i < IN_DIM; ++i) s = fmaf(sin_[i], wobs[HD + i], s);
    ob[0] = s;
  }
}

// ---------------- GEMM: z = sigmoid(h0@Wz+zb), rh = sigmoid(h0@Wr+rb)*h0 ----
#define BM 128
#define BN 64
#define BK 32
#define APAD 4
#define BPAD 4

__global__ __launch_bounds__(256) void gemm_zr_kernel(
    const float* __restrict__ A,    // h0: KP x HD
    const float* __restrict__ Wz,   // 1536 x 1024 (rows 0..1023 used)
    const float* __restrict__ Wr,
    const float* __restrict__ zbias, const float* __restrict__ rbias,
    float* __restrict__ zout,       // KP x HD
    float* __restrict__ rhout) {    // KP x HD
  __shared__ float As[BK][BM + APAD];   // row stride 132 floats = 528B, 16B aligned
  __shared__ float Bzs[BK][BN + BPAD];  // row stride 68 floats = 272B, 16B aligned
  __shared__ float Brs[BK][BN + BPAD];
  int t = threadIdx.x;
  int tx = t & 15, ty = t >> 4;
  int row0 = blockIdx.x * BM, col0 = blockIdx.y * BN;

  float acc_z[8][4] = {};
  float acc_r[8][4] = {};

  for (int kb = 0; kb < HD; kb += BK) {
#pragma unroll
    for (int p = 0; p < 4; ++p) {
      int r = (t >> 3) + p * 32;
      int q = (t & 7) * 4;
      float4 v = *(const float4*)&A[(size_t)(row0 + r) * HD + kb + q];
      As[q + 0][r] = v.x; As[q + 1][r] = v.y; As[q + 2][r] = v.z; As[q + 3][r] = v.w;
    }
#pragma unroll
    for (int p = 0; p < 2; ++p) {
      int r = (t >> 4) + p * 16;
      int q = (t & 15) * 4;
      *(float4*)&Bzs[r][q] = *(const float4*)&Wz[(size_t)(kb + r) * HD + col0 + q];
      *(float4*)&Brs[r][q] = *(const float4*)&Wr[(size_t)(kb + r) * HD + col0 + q];
    }
    __syncthreads();
#pragma unroll 4
    for (int kk = 0; kk < BK; ++kk) {
      float4 a0 = *(const float4*)&As[kk][ty * 8];
      float4 a1 = *(const float4*)&As[kk][ty * 8 + 4];
      float4 bz = *(const float4*)&Bzs[kk][tx * 4];
      float4 br = *(const float4*)&Brs[kk][tx * 4];
      float a[8] = {a0.x, a0.y, a0.z, a0.w, a1.x, a1.y, a1.z, a1.w};
      float bzv[4] = {bz.x, bz.y, bz.z, bz.w};
      float brv[4] = {br.x, br.y, br.z, br.w};
#pragma unroll
      for (int i = 0; i < 8; ++i)
#pragma unroll
        for (int j = 0; j < 4; ++j) {
          acc_z[i][j] = fmaf(a[i], bzv[j], acc_z[i][j]);
          acc_r[i][j] = fmaf(a[i], brv[j], acc_r[i][j]);
        }
    }
    __syncthreads();
  }
#pragma unroll
  for (int i = 0; i < 8; ++i) {
    int row = row0 + ty * 8 + i;
    float4 h4 = *(const float4*)&A[(size_t)row * HD + col0 + tx * 4];
    float h[4] = {h4.x, h4.y, h4.z, h4.w};
#pragma unroll
    for (int j = 0; j < 4; ++j) {
      int col = col0 + tx * 4 + j;
      float z = 1.0f / (1.0f + expf(-(acc_z[i][j] + zbias[col])));
      float r = 1.0f / (1.0f + expf(-(acc_r[i][j] + rbias[col])));
      zout[(size_t)row * HD + col] = z;
      rhout[(size_t)row * HD + col] = r * h[j];
    }
  }
}

// ---------------- GEMM: n_pre = rh@Wn[:1024] + nb; fused h1 epilogue --------
__global__ __launch_bounds__(256) void gemm_n_kernel(
    const float* __restrict__ A,     // rh: KP x HD
    const float* __restrict__ Wn,    // 1536 x 2048 (rows 0..1023 used)
    const float* __restrict__ nbias, // 2048
    const float* __restrict__ h0,
    const float* __restrict__ eps,
    const float* __restrict__ zbuf,  // z: KP x HD
    float* __restrict__ h1out) {     // KP x HD
  __shared__ float As[BK][BM + APAD];
  __shared__ float Bms[BK][BN + BPAD];
  __shared__ float Bvs[BK][BN + BPAD];
  int t = threadIdx.x;
  int tx = t & 15, ty = t >> 4;
  int row0 = blockIdx.x * BM, col0 = blockIdx.y * BN;

  float acc_m[8][4] = {};
  float acc_v[8][4] = {};

  for (int kb = 0; kb < HD; kb += BK) {
#pragma unroll
    for (int p = 0; p < 4; ++p) {
      int r = (t >> 3) + p * 32;
      int q = (t & 7) * 4;
      float4 v = *(const float4*)&A[(size_t)(row0 + r) * HD + kb + q];
      As[q + 0][r] = v.x; As[q + 1][r] = v.y; As[q + 2][r] = v.z; As[q + 3][r] = v.w;
    }
#pragma unroll
    for (int p = 0; p < 2; ++p) {
      int r = (t >> 4) + p * 16;
      int q = (t & 15) * 4;
      *(float4*)&Bms[r][q] = *(const float4*)&Wn[(size_t)(kb + r) * 2048 + col0 + q];
      *(float4*)&Bvs[r][q] = *(const float4*)&Wn[(size_t)(kb + r) * 2048 + 1024 + col0 + q];
    }
    __syncthreads();
#pragma unroll 4
    for (int kk = 0; kk < BK; ++kk) {
      float4 a0 = *(const float4*)&As[kk][ty * 8];
      float4 a1 = *(const float4*)&As[kk][ty * 8 + 4];
      float4 bm4 = *(const float4*)&Bms[kk][tx * 4];
      float4 bv4 = *(const float4*)&Bvs[kk][tx * 4];
      float a[8] = {a0.x, a0.y, a0.z, a0.w, a1.x, a1.y, a1.z, a1.w};
      float bm[4] = {bm4.x, bm4.y, bm4.z, bm4.w};
      float bv[4] = {bv4.x, bv4.y, bv4.z, bv4.w};
#pragma unroll
      for (int i = 0; i < 8; ++i)
#pragma unroll
        for (int j = 0; j < 4; ++j) {
          acc_m[i][j] = fmaf(a[i], bm[j], acc_m[i][j]);
          acc_v[i][j] = fmaf(a[i], bv[j], acc_v[i][j]);
        }
    }
    __syncthreads();
  }
#pragma unroll
  for (int i = 0; i < 8; ++i) {
    int row = row0 + ty * 8 + i;
    float4 h4 = *(const float4*)&h0[(size_t)row * HD + col0 + tx * 4];
    float4 e4 = *(const float4*)&eps[(size_t)row * HD + col0 + tx * 4];
    float hv[4] = {h4.x, h4.y, h4.z, h4.w};
    float ev[4] = {e4.x, e4.y, e4.z, e4.w};
#pragma unroll
    for (int j = 0; j < 4; ++j) {
      int col = col0 + tx * 4 + j;
      float mu = acc_m[i][j] + nbias[col];
      float var = acc_v[i][j] + nbias[1024 + col];
      float sp = fmaxf(var, 0.0f) + log1pf(expf(-fabsf(var)));
      float n = tanhf(mu + ev[j] * sp);
      float z = zbuf[(size_t)row * HD + col];
      h1out[(size_t)row * HD + col] = (1.0f - z) * n + z * hv[j];
    }
  }
}

// ---------------- score: s = h1@wobs[:1024] + ob + p0 ----------------------
__global__ __launch_bounds__(256) void score_kernel(
    const float* __restrict__ h1, const float* __restrict__ wobs,
    const float* __restrict__ ob, const float* __restrict__ p0,
    float* __restrict__ s) {
  __shared__ float w[HD];
  int t = threadIdx.x;
  for (int i = t; i < HD; i += 256) w[i] = wobs[i];
  __syncthreads();
  int wave = t >> 6, lane = t & 63;
  int row = blockIdx.x * 4 + wave;
  float acc = 0.0f;
  for (int c = lane * 4; c < HD; c += 256) {
    float4 v = *(const float4*)&h1[(size_t)row * HD + c];
    acc = fmaf(v.x, w[c], acc);
    acc = fmaf(v.y, w[c + 1], acc);
    acc = fmaf(v.z, w[c + 2], acc);
    acc = fmaf(v.w, w[c + 3], acc);
  }
#pragma unroll
  for (int off = 32; off; off >>= 1) acc += __shfl_down(acc, off);
  if (lane == 0) s[row] = acc + ob[0] + p0[row];
}

// ---------------- log_softmax over K + categorical logits + Lmax -----------
__global__ __launch_bounds__(1024) void softmax_kernel(
    const float* __restrict__ s, float* __restrict__ p1v,
    float* __restrict__ logits, float* __restrict__ lmaxp) {
  __shared__ float red[1024];
  int t = threadIdx.x;
  float m = -INFINITY;
  for (int k = t; k < KP; k += 1024) m = fmaxf(m, s[k]);
  red[t] = m; __syncthreads();
  for (int o = 512; o; o >>= 1) { if (t < o) red[t] = fmaxf(red[t], red[t + o]); __syncthreads(); }
  m = red[0]; __syncthreads();
  float sum = 0.0f;
  for (int k = t; k < KP; k += 1024) sum += expf(s[k] - m);
  red[t] = sum; __syncthreads();
  for (int o = 512; o; o >>= 1) { if (t < o) red[t] += red[t + o]; __syncthreads(); }
  float ls = logf(red[0]);
  for (int k = t; k < KP; k += 1024) {
    float p = s[k] - m - ls;
    p1v[k] = p;
    logits[k] = logf(0.5f * expf(p) + (0.5f / KP));
  }
  // max logit in closed form: p_max = -ls  (since max s == m)
  if (t == 0) lmaxp[0] = logf(0.5f * expf(-ls) + (0.5f / KP));
}

// ---------------- categorical (partitionable threefry) with exact pruning ---
// bits[i] = o0 ^ o1 of threefry2x32(key=(0,42), counts=(0, r*16384+c))
// gumbel is monotone in (bits>>9); prune by integer mantissa threshold derived
// from an exact sample max B0 and the global max logit (conservative margins).
__global__ __launch_bounds__(256) void categorical_kernel(
    const float* __restrict__ logits, const float* __restrict__ lmaxp,
    int* __restrict__ idx) {
  __shared__ float sv[256];
  __shared__ int si[256];
  __shared__ uint32_t sthr;
  int r = blockIdx.x;  // 0..16383
  int t = threadIdx.x;
  uint32_t base = (uint32_t)r << 14;

  // sample phase: element c = t (exact evaluation)
  float best; int bi;
  {
    uint32_t o0, o1;
    threefry2x32(0u, base | (uint32_t)t, o0, o1);
    best = gumbel_from_bits(o0 ^ o1) + logits[t];
    bi = t;
  }
  sv[t] = best; __syncthreads();
  for (int o = 128; o; o >>= 1) { if (t < o) sv[t] = fmaxf(sv[t], sv[t + o]); __syncthreads(); }
  if (t == 0) {
    float B0 = sv[0];
    // candidate can win only if w = -log(u) < exp(l - B0) <= exp(Lmax - B0)
    float wth = expf(lmaxp[0] + 1e-3f - B0);     // inflated (conservative)
    float omu = -expm1f(-wth);                   // 1 - exp(-wth), precise
    float delta = 8388608.0f * omu;              // 2^23 * (1 - u_threshold)
    uint32_t thr;
    if (delta >= 8388592.0f) thr = 0u;           // no pruning possible
    else {
      thr = 8388608u - (uint32_t)delta;
      thr = (thr > 24u) ? (thr - 24u) : 0u;      // extra ulp slack
    }
    sthr = thr;
  }
  __syncthreads();
  uint32_t thr = sthr;

  for (int c = 256 + t; c < KP; c += 256) {
    uint32_t o0, o1;
    threefry2x32(0u, base | (uint32_t)c, o0, o1);
    uint32_t bits = o0 ^ o1;
    if ((bits >> 9) >= thr) {
      float g = gumbel_from_bits(bits) + logits[c];
      if (g > best) { best = g; bi = c; }
    }
  }
  sv[t] = best; si[t] = bi; __syncthreads();
  for (int o = 128; o; o >>= 1) {
    if (t < o) {
      if (sv[t + o] > sv[t] || (sv[t + o] == sv[t] && si[t + o] < si[t])) {
        sv[t] = sv[t + o]; si[t] = si[t + o];
      }
    }
    __syncthreads();
  }
  if (t == 0) idx[r] = si[0];
}

// ---------------- resample weights + final p1 ------------------------------
__global__ __launch_bounds__(1024) void resample_kernel(
    const float* __restrict__ p1v, const int* __restrict__ idx,
    float* __restrict__ pn, float* __restrict__ p1out, float* __restrict__ wexp) {
  __shared__ float red[1024];
  int t = threadIdx.x;
  float m = -INFINITY;
  for (int k = t; k < KP; k += 1024) {
    float pv = p1v[idx[k]];
    float w = expf(pv);
    float v = logf(w / (0.5f * w + (0.5f / KP)));
    pn[k] = v;
    m = fmaxf(m, v);
  }
  red[t] = m; __syncthreads();
  for (int o = 512; o; o >>= 1) { if (t < o) red[t] = fmaxf(red[t], red[t + o]); __syncthreads(); }
  m = red[0]; __syncthreads();
  float sum = 0.0f;
  for (int k = t; k < KP; k += 1024) sum += expf(pn[k] - m);
  red[t] = sum; __syncthreads();
  for (int o = 512; o; o >>= 1) { if (t < o) red[t] += red[t + o]; __syncthreads(); }
  float lse = m + logf(red[0]);
  for (int k = t; k < KP; k += 1024) {
    float v = pn[k] - lse;
    p1out[k] = v;
    wexp[k] = expf(v);
  }
}

// ---------------- gather h1 + per-block partial weighted sums --------------
__global__ __launch_bounds__(256) void gather_kernel(
    const float* __restrict__ h1pre, const int* __restrict__ idx,
    const float* __restrict__ wexp, float* __restrict__ h1out,
    float* __restrict__ partials) {
  int t = threadIdx.x;
  int k0 = blockIdx.x * 64;
  float part[4] = {0.f, 0.f, 0.f, 0.f};
  for (int kk = 0; kk < 64; ++kk) {
    int k = k0 + kk;
    int src = idx[k];
    float w = wexp[k];
#pragma unroll
    for (int c = 0; c < 4; ++c) {
      float v = h1pre[(size_t)src * HD + t + c * 256];
      h1out[(size_t)k * HD + t + c * 256] = v;
      part[c] = fmaf(w, v, part[c]);
    }
  }
#pragma unroll
  for (int c = 0; c < 4; ++c) partials[(size_t)blockIdx.x * HD + t + c * 256] = part[c];
}

__global__ __launch_bounds__(256) void reduce_mean_kernel(
    const float* __restrict__ partials, float* __restrict__ mean_hid) {
  int j = blockIdx.x * 256 + threadIdx.x;
  float s = 0.0f;
  for (int b = 0; b < 256; ++b) s += partials[(size_t)b * HD + j];
  mean_hid[j] = s;
}

// ---------------- final 2-layer head ---------------------------------------
__global__ __launch_bounds__(64) void final_kernel(
    const float* __restrict__ mean_hid,
    const float* __restrict__ wh1, const float* __restrict__ bh1,
    const float* __restrict__ wh2, const float* __restrict__ bh2,
    float* __restrict__ out) {
  __shared__ float hrelu[24];
  int t = threadIdx.x;
  if (t < 24) {
    float s = bh1[t];
    for (int i = 0; i < HD; ++i) s = fmaf(mean_hid[i], wh1[i * 24 + t], s);
    hrelu[t] = fmaxf(s, 0.0f);
  }
  __syncthreads();
  if (t < 2) {
    float s = bh2[t];
    for (int j = 0; j < 24; ++j) s = fmaf(hrelu[j], wh2[j * 2 + t], s);
    out[t] = s;
  }
}

extern "C" void kernel_launch(void* const* d_in, const int* in_sizes, int n_in,
                              void* d_out, int out_size, void* d_ws, size_t ws_size,
                              hipStream_t stream) {
  (void)in_sizes; (void)n_in; (void)out_size; (void)ws_size;
  const float* input_ = (const float*)d_in[0];
  const float* h0    = (const float*)d_in[1];
  const float* p0    = (const float*)d_in[2];
  const float* eps   = (const float*)d_in[3];
  const float* w_z   = (const float*)d_in[4];
  const float* b_z   = (const float*)d_in[5];
  const float* w_r   = (const float*)d_in[6];
  const float* b_r   = (const float*)d_in[7];
  const float* w_n   = (const float*)d_in[8];
  const float* b_n   = (const float*)d_in[9];
  const float* w_obs = (const float*)d_in[10];
  const float* b_obs = (const float*)d_in[11];
  const float* w_h1  = (const float*)d_in[12];
  const float* b_h1  = (const float*)d_in[13];
  const float* w_h2  = (const float*)d_in[14];
  const float* b_h2  = (const float*)d_in[15];

  float* out = (float*)d_out;
  float* out_loc = out;                       // 2
  float* out_h1  = out + 2;                   // KP*HD  (also used as z scratch)
  float* out_p1  = out + 2 + (size_t)KP * HD; // KP

  float* ws = (float*)d_ws;
  float* rh      = ws;                          // KP*HD
  float* h1pre   = ws + (size_t)KP * HD;        // KP*HD
  float* zb      = ws + 2 * (size_t)KP * HD;    // 1024
  float* rb      = zb + 1024;                   // 1024
  float* nb      = rb + 1024;                   // 2048
  float* ob      = nb + 2048;                   // [0]=obs bias, [8]=Lmax
  float* sbuf    = ob + 16;                     // KP
  float* p1v     = sbuf + KP;                   // KP
  float* logits  = p1v + KP;                    // KP
  float* pn      = logits + KP;                 // KP
  float* wexpb   = pn + KP;                     // KP
  float* mean_hid= wexpb + KP;                  // 1024
  float* partials= mean_hid + 1024;             // 256*1024
  int*   idxb    = (int*)(partials + 256 * HD); // KP ints

  bias_kernel<<<17, 256, 0, stream>>>(input_, w_z, b_z, w_r, b_r, w_n, b_n,
                                      w_obs, b_obs, zb, rb, nb, ob);

  dim3 g1(KP / BM, HD / BN);
  gemm_zr_kernel<<<g1, 256, 0, stream>>>(h0, w_z, w_r, zb, rb, out_h1 /*z*/, rh);

  gemm_n_kernel<<<g1, 256, 0, stream>>>(rh, w_n, nb, h0, eps, out_h1 /*z*/, h1pre);

  score_kernel<<<KP / 4, 256, 0, stream>>>(h1pre, w_obs, ob, p0, sbuf);

  softmax_kernel<<<1, 1024, 0, stream>>>(sbuf, p1v, logits, ob + 8);

  categorical_kernel<<<KP, 256, 0, stream>>>(logits, ob + 8, idxb);

  resample_kernel<<<1, 1024, 0, stream>>>(p1v, idxb, pn, out_p1, wexpb);

  gather_kernel<<<KP / 64, 256, 0, stream>>>(h1pre, idxb, wexpb, out_h1, partials);

  reduce_mean_kernel<<<4, 256, 0, stream>>>(partials, mean_hid);

  final_kernel<<<1, 64, 0, stream>>>(mean_hid, w_h1, b_h1, w_h2, b_h2, out_loc);
}

// Round 4
// 1302.047 us; speedup vs baseline: 2.0470x; 1.8085x over previous
//
#include <hip/hip_runtime.h>
#include <math.h>
#include <stdint.h>

#define KP 16384
#define IN_DIM 512
#define HD 1024

typedef _Float16 f16x8 __attribute__((ext_vector_type(8)));
typedef float f32x4 __attribute__((ext_vector_type(4)));

// ---------------- threefry2x32 (JAX key(42) => k0=0, k1=42) ----------------
__device__ __forceinline__ uint32_t rotl(uint32_t x, uint32_t r) {
  return (x << r) | (x >> (32u - r));
}

__device__ __forceinline__ void threefry2x32(uint32_t x0, uint32_t x1,
                                             uint32_t& o0, uint32_t& o1) {
  const uint32_t ks0 = 0u, ks1 = 42u, ks2 = 0u ^ 42u ^ 0x1BD11BDAu;
  x0 += ks0; x1 += ks1;
#define TF_R4(r0, r1, r2, r3) \
  x0 += x1; x1 = rotl(x1, r0); x1 ^= x0; \
  x0 += x1; x1 = rotl(x1, r1); x1 ^= x0; \
  x0 += x1; x1 = rotl(x1, r2); x1 ^= x0; \
  x0 += x1; x1 = rotl(x1, r3); x1 ^= x0;
  TF_R4(13u,15u,26u,6u);   x0 += ks1; x1 += ks2 + 1u;
  TF_R4(17u,29u,16u,24u);  x0 += ks2; x1 += ks0 + 2u;
  TF_R4(13u,15u,26u,6u);   x0 += ks0; x1 += ks1 + 3u;
  TF_R4(17u,29u,16u,24u);  x0 += ks1; x1 += ks2 + 4u;
  TF_R4(13u,15u,26u,6u);   x0 += ks2; x1 += ks0 + 5u;
#undef TF_R4
  o0 = x0; o1 = x1;
}

__device__ __forceinline__ float gumbel_from_bits(uint32_t b) {
  uint32_t ub = (b >> 9) | 0x3f800000u;
  float u = __uint_as_float(ub) - 1.0f;
  u = fmaxf(u, 1.1754943508222875e-38f);
  return -logf(-logf(u));
}

// ---------------- bias precompute: input_ @ W[1024:,:] + b ----------------
__global__ __launch_bounds__(256) void bias_kernel(
    const float* __restrict__ in,
    const float* __restrict__ wz, const float* __restrict__ bz,
    const float* __restrict__ wr, const float* __restrict__ br,
    const float* __restrict__ wn, const float* __restrict__ bn,
    const float* __restrict__ wobs, const float* __restrict__ bobs,
    float* __restrict__ zb, float* __restrict__ rb,
    float* __restrict__ nb, float* __restrict__ ob) {
  __shared__ float sin_[IN_DIM];
  int t = threadIdx.x;
  for (int i = t; i < IN_DIM; i += 256) sin_[i] = in[i];
  __syncthreads();
  int gid = blockIdx.x * 256 + t;
  if (gid < 1024) {
    float s = bz[gid];
    for (int i = 0; i < IN_DIM; ++i) s = fmaf(sin_[i], wz[(HD + i) * HD + gid], s);
    zb[gid] = s;
  } else if (gid < 2048) {
    int j = gid - 1024;
    float s = br[j];
    for (int i = 0; i < IN_DIM; ++i) s = fmaf(sin_[i], wr[(HD + i) * HD + j], s);
    rb[j] = s;
  } else if (gid < 4096) {
    int j = gid - 2048;
    float s = bn[j];
    for (int i = 0; i < IN_DIM; ++i) s = fmaf(sin_[i], wn[(HD + i) * 2048 + j], s);
    nb[j] = s;
  } else if (gid == 4096) {
    float s = bobs[0];
    for (int i = 0; i < IN_DIM; ++i) s = fmaf(sin_[i], wobs[HD + i], s);
    ob[0] = s;
  }
}

// ---------------- weight transpose + fp16 2-term split (x64 prescale) ------
// out[n][k] pair (hi, lo) with  w*64 == hi + lo/2048  (+O(2^-22))
__global__ __launch_bounds__(256) void splitw_kernel(
    const float* __restrict__ wz, const float* __restrict__ wr,
    const float* __restrict__ wn,
    _Float16* __restrict__ zHi, _Float16* __restrict__ zLo,
    _Float16* __restrict__ rHi, _Float16* __restrict__ rLo,
    _Float16* __restrict__ mHi, _Float16* __restrict__ mLo,
    _Float16* __restrict__ vHi, _Float16* __restrict__ vLo) {
  __shared__ float tile[32][33];
  int m = blockIdx.z;
  const float* src; int ld, cofs; _Float16 *oh, *ol;
  if (m == 0)      { src = wz; ld = 1024; cofs = 0;    oh = zHi; ol = zLo; }
  else if (m == 1) { src = wr; ld = 1024; cofs = 0;    oh = rHi; ol = rLo; }
  else if (m == 2) { src = wn; ld = 2048; cofs = 0;    oh = mHi; ol = mLo; }
  else             { src = wn; ld = 2048; cofs = 1024; oh = vHi; ol = vLo; }
  int k0 = blockIdx.x * 32, n0 = blockIdx.y * 32;
  int tx = threadIdx.x & 31, ty = threadIdx.x >> 5;
#pragma unroll
  for (int i = 0; i < 4; ++i) {
    int k = ty * 4 + i;
    tile[k][tx] = src[(size_t)(k0 + k) * ld + cofs + n0 + tx];
  }
  __syncthreads();
#pragma unroll
  for (int i = 0; i < 4; ++i) {
    int n = ty * 4 + i;
    float v = tile[tx][n] * 64.0f;
    _Float16 h = (_Float16)v;
    _Float16 l = (_Float16)((v - (float)h) * 2048.0f);
    oh[(size_t)(n0 + n) * 1024 + k0 + tx] = h;
    ol[(size_t)(n0 + n) * 1024 + k0 + tx] = l;
  }
}

// ---------------- MFMA split-GEMM #1: z & rh ------------------------------
#define LDH 40   // halfs per LDS row (32 data + 8 pad); 80B, 16B-multiple

__global__ __launch_bounds__(256, 2) void gemm_zr_mfma(
    const float* __restrict__ A,  // h0: KP x HD fp32 (also epilogue h0)
    const _Float16* __restrict__ BzHi, const _Float16* __restrict__ BzLo,
    const _Float16* __restrict__ BrHi, const _Float16* __restrict__ BrLo,
    const float* __restrict__ zbias, const float* __restrict__ rbias,
    float* __restrict__ zout, float* __restrict__ rhout) {
  __shared__ __align__(16) _Float16 Ah[128 * LDH], Al[128 * LDH];
  __shared__ __align__(16) _Float16 B0h[64 * LDH], B0l[64 * LDH];
  __shared__ __align__(16) _Float16 B1h[64 * LDH], B1l[64 * LDH];
  int t = threadIdx.x;
  int row0 = blockIdx.x * 128, col0 = blockIdx.y * 64;
  int wave = t >> 6, lane = t & 63;
  int lr = lane & 15, hh = lane >> 4;
  int WR = (wave >> 1) * 64, WC = (wave & 1) * 32;

  f32x4 acc0[4][2][2] = {};
  f32x4 acc1[4][2][2] = {};

  for (int kb = 0; kb < 1024; kb += 32) {
#pragma unroll
    for (int p = 0; p < 2; ++p) {
      int id = t + p * 256;
      int row = id >> 2, kc = id & 3;
      const float* g = &A[(size_t)(row0 + row) * 1024 + kb + kc * 8];
      float4 v0 = *(const float4*)g;
      float4 v1 = *(const float4*)(g + 4);
      float vv[8] = {v0.x, v0.y, v0.z, v0.w, v1.x, v1.y, v1.z, v1.w};
      f16x8 hi, lo;
#pragma unroll
      for (int j = 0; j < 8; ++j) {
        _Float16 h = (_Float16)vv[j];
        hi[j] = h;
        lo[j] = (_Float16)((vv[j] - (float)h) * 2048.0f);
      }
      *(f16x8*)&Ah[row * LDH + kc * 8] = hi;
      *(f16x8*)&Al[row * LDH + kc * 8] = lo;
    }
    {
      int n = t >> 2, kc = t & 3;
      size_t gofs = (size_t)(col0 + n) * 1024 + kb + kc * 8;
      int lofs = n * LDH + kc * 8;
      *(f16x8*)&B0h[lofs] = *(const f16x8*)&BzHi[gofs];
      *(f16x8*)&B0l[lofs] = *(const f16x8*)&BzLo[gofs];
      *(f16x8*)&B1h[lofs] = *(const f16x8*)&BrHi[gofs];
      *(f16x8*)&B1l[lofs] = *(const f16x8*)&BrLo[gofs];
    }
    __syncthreads();
    f16x8 ah[4], al[4], bh[2][2], bl[2][2];
#pragma unroll
    for (int mt = 0; mt < 4; ++mt) {
      int r = WR + mt * 16 + lr;
      ah[mt] = *(f16x8*)&Ah[r * LDH + hh * 8];
      al[mt] = *(f16x8*)&Al[r * LDH + hh * 8];
    }
#pragma unroll
    for (int nt = 0; nt < 2; ++nt) {
      int c = WC + nt * 16 + lr;
      bh[0][nt] = *(f16x8*)&B0h[c * LDH + hh * 8];
      bl[0][nt] = *(f16x8*)&B0l[c * LDH + hh * 8];
      bh[1][nt] = *(f16x8*)&B1h[c * LDH + hh * 8];
      bl[1][nt] = *(f16x8*)&B1l[c * LDH + hh * 8];
    }
#pragma unroll
    for (int mt = 0; mt < 4; ++mt)
#pragma unroll
      for (int nt = 0; nt < 2; ++nt)
#pragma unroll
        for (int m = 0; m < 2; ++m) {
          acc0[mt][nt][m] = __builtin_amdgcn_mfma_f32_16x16x32_f16(ah[mt], bh[m][nt], acc0[mt][nt][m], 0, 0, 0);
          acc1[mt][nt][m] = __builtin_amdgcn_mfma_f32_16x16x32_f16(ah[mt], bl[m][nt], acc1[mt][nt][m], 0, 0, 0);
          acc1[mt][nt][m] = __builtin_amdgcn_mfma_f32_16x16x32_f16(al[mt], bh[m][nt], acc1[mt][nt][m], 0, 0, 0);
        }
    __syncthreads();
  }
  const float INV = 1.0f / 2048.0f, WS = 1.0f / 64.0f;
#pragma unroll
  for (int mt = 0; mt < 4; ++mt)
#pragma unroll
    for (int nt = 0; nt < 2; ++nt) {
      int col = col0 + WC + nt * 16 + lr;
#pragma unroll
      for (int q = 0; q < 4; ++q) {
        int row = row0 + WR + mt * 16 + hh * 4 + q;
        float vz = (acc0[mt][nt][0][q] + acc1[mt][nt][0][q] * INV) * WS + zbias[col];
        float vr = (acc0[mt][nt][1][q] + acc1[mt][nt][1][q] * INV) * WS + rbias[col];
        float z = 1.0f / (1.0f + expf(-vz));
        float r = 1.0f / (1.0f + expf(-vr));
        float hv = A[(size_t)row * 1024 + col];
        zout[(size_t)row * 1024 + col] = z;
        rhout[(size_t)row * 1024 + col] = r * hv;
      }
    }
}

// ---------------- MFMA split-GEMM #2: n_pre (mu,var) + h1 epilogue ---------
__global__ __launch_bounds__(256, 2) void gemm_n_mfma(
    const float* __restrict__ A,  // rh: KP x HD fp32
    const _Float16* __restrict__ BmHi, const _Float16* __restrict__ BmLo,
    const _Float16* __restrict__ BvHi, const _Float16* __restrict__ BvLo,
    const float* __restrict__ nbias,
    const float* __restrict__ h0, const float* __restrict__ eps,
    const float* __restrict__ zbuf, float* __restrict__ h1out) {
  __shared__ __align__(16) _Float16 Ah[128 * LDH], Al[128 * LDH];
  __shared__ __align__(16) _Float16 B0h[64 * LDH], B0l[64 * LDH];
  __shared__ __align__(16) _Float16 B1h[64 * LDH], B1l[64 * LDH];
  int t = threadIdx.x;
  int row0 = blockIdx.x * 128, col0 = blockIdx.y * 64;
  int wave = t >> 6, lane = t & 63;
  int lr = lane & 15, hh = lane >> 4;
  int WR = (wave >> 1) * 64, WC = (wave & 1) * 32;

  f32x4 acc0[4][2][2] = {};
  f32x4 acc1[4][2][2] = {};

  for (int kb = 0; kb < 1024; kb += 32) {
#pragma unroll
    for (int p = 0; p < 2; ++p) {
      int id = t + p * 256;
      int row = id >> 2, kc = id & 3;
      const float* g = &A[(size_t)(row0 + row) * 1024 + kb + kc * 8];
      float4 v0 = *(const float4*)g;
      float4 v1 = *(const float4*)(g + 4);
      float vv[8] = {v0.x, v0.y, v0.z, v0.w, v1.x, v1.y, v1.z, v1.w};
      f16x8 hi, lo;
#pragma unroll
      for (int j = 0; j < 8; ++j) {
        _Float16 h = (_Float16)vv[j];
        hi[j] = h;
        lo[j] = (_Float16)((vv[j] - (float)h) * 2048.0f);
      }
      *(f16x8*)&Ah[row * LDH + kc * 8] = hi;
      *(f16x8*)&Al[row * LDH + kc * 8] = lo;
    }
    {
      int n = t >> 2, kc = t & 3;
      size_t gofs = (size_t)(col0 + n) * 1024 + kb + kc * 8;
      int lofs = n * LDH + kc * 8;
      *(f16x8*)&B0h[lofs] = *(const f16x8*)&BmHi[gofs];
      *(f16x8*)&B0l[lofs] = *(const f16x8*)&BmLo[gofs];
      *(f16x8*)&B1h[lofs] = *(const f16x8*)&BvHi[gofs];
      *(f16x8*)&B1l[lofs] = *(const f16x8*)&BvLo[gofs];
    }
    __syncthreads();
    f16x8 ah[4], al[4], bh[2][2], bl[2][2];
#pragma unroll
    for (int mt = 0; mt < 4; ++mt) {
      int r = WR + mt * 16 + lr;
      ah[mt] = *(f16x8*)&Ah[r * LDH + hh * 8];
      al[mt] = *(f16x8*)&Al[r * LDH + hh * 8];
    }
#pragma unroll
    for (int nt = 0; nt < 2; ++nt) {
      int c = WC + nt * 16 + lr;
      bh[0][nt] = *(f16x8*)&B0h[c * LDH + hh * 8];
      bl[0][nt] = *(f16x8*)&B0l[c * LDH + hh * 8];
      bh[1][nt] = *(f16x8*)&B1h[c * LDH + hh * 8];
      bl[1][nt] = *(f16x8*)&B1l[c * LDH + hh * 8];
    }
#pragma unroll
    for (int mt = 0; mt < 4; ++mt)
#pragma unroll
      for (int nt = 0; nt < 2; ++nt)
#pragma unroll
        for (int m = 0; m < 2; ++m) {
          acc0[mt][nt][m] = __builtin_amdgcn_mfma_f32_16x16x32_f16(ah[mt], bh[m][nt], acc0[mt][nt][m], 0, 0, 0);
          acc1[mt][nt][m] = __builtin_amdgcn_mfma_f32_16x16x32_f16(ah[mt], bl[m][nt], acc1[mt][nt][m], 0, 0, 0);
          acc1[mt][nt][m] = __builtin_amdgcn_mfma_f32_16x16x32_f16(al[mt], bh[m][nt], acc1[mt][nt][m], 0, 0, 0);
        }
    __syncthreads();
  }
  const float INV = 1.0f / 2048.0f, WS = 1.0f / 64.0f;
#pragma unroll
  for (int mt = 0; mt < 4; ++mt)
#pragma unroll
    for (int nt = 0; nt < 2; ++nt) {
      int col = col0 + WC + nt * 16 + lr;
#pragma unroll
      for (int q = 0; q < 4; ++q) {
        int row = row0 + WR + mt * 16 + hh * 4 + q;
        size_t off = (size_t)row * 1024 + col;
        float mu = (acc0[mt][nt][0][q] + acc1[mt][nt][0][q] * INV) * WS + nbias[col];
        float var = (acc0[mt][nt][1][q] + acc1[mt][nt][1][q] * INV) * WS + nbias[1024 + col];
        float sp = fmaxf(var, 0.0f) + log1pf(expf(-fabsf(var)));
        float n = tanhf(mu + eps[off] * sp);
        float z = zbuf[off];
        h1out[off] = (1.0f - z) * n + z * h0[off];
      }
    }
}

// ---------------- score: s = h1@wobs[:1024] + ob + p0 ----------------------
__global__ __launch_bounds__(256) void score_kernel(
    const float* __restrict__ h1, const float* __restrict__ wobs,
    const float* __restrict__ ob, const float* __restrict__ p0,
    float* __restrict__ s) {
  __shared__ float w[HD];
  int t = threadIdx.x;
  for (int i = t; i < HD; i += 256) w[i] = wobs[i];
  __syncthreads();
  int wave = t >> 6, lane = t & 63;
  int row = blockIdx.x * 4 + wave;
  float acc = 0.0f;
  for (int c = lane * 4; c < HD; c += 256) {
    float4 v = *(const float4*)&h1[(size_t)row * HD + c];
    acc = fmaf(v.x, w[c], acc);
    acc = fmaf(v.y, w[c + 1], acc);
    acc = fmaf(v.z, w[c + 2], acc);
    acc = fmaf(v.w, w[c + 3], acc);
  }
#pragma unroll
  for (int off = 32; off; off >>= 1) acc += __shfl_down(acc, off);
  if (lane == 0) s[row] = acc + ob[0] + p0[row];
}

// ---------------- log_softmax over K + categorical logits + Lmax -----------
__global__ __launch_bounds__(1024) void softmax_kernel(
    const float* __restrict__ s, float* __restrict__ p1v,
    float* __restrict__ logits, float* __restrict__ lmaxp) {
  __shared__ float red[1024];
  int t = threadIdx.x;
  float m = -INFINITY;
  for (int k = t; k < KP; k += 1024) m = fmaxf(m, s[k]);
  red[t] = m; __syncthreads();
  for (int o = 512; o; o >>= 1) { if (t < o) red[t] = fmaxf(red[t], red[t + o]); __syncthreads(); }
  m = red[0]; __syncthreads();
  float sum = 0.0f;
  for (int k = t; k < KP; k += 1024) sum += expf(s[k] - m);
  red[t] = sum; __syncthreads();
  for (int o = 512; o; o >>= 1) { if (t < o) red[t] += red[t + o]; __syncthreads(); }
  float ls = logf(red[0]);
  for (int k = t; k < KP; k += 1024) {
    float p = s[k] - m - ls;
    p1v[k] = p;
    logits[k] = logf(0.5f * expf(p) + (0.5f / KP));
  }
  if (t == 0) lmaxp[0] = logf(0.5f * expf(-ls) + (0.5f / KP));
}

// ---------------- categorical (partitionable threefry) with exact pruning ---
__global__ __launch_bounds__(256) void categorical_kernel(
    const float* __restrict__ logits, const float* __restrict__ lmaxp,
    int* __restrict__ idx) {
  __shared__ float sv[256];
  __shared__ int si[256];
  __shared__ uint32_t sthr;
  int r = blockIdx.x;
  int t = threadIdx.x;
  uint32_t base = (uint32_t)r << 14;

  float best; int bi;
  {
    uint32_t o0, o1;
    threefry2x32(0u, base | (uint32_t)t, o0, o1);
    best = gumbel_from_bits(o0 ^ o1) + logits[t];
    bi = t;
  }
  sv[t] = best; __syncthreads();
  for (int o = 128; o; o >>= 1) { if (t < o) sv[t] = fmaxf(sv[t], sv[t + o]); __syncthreads(); }
  if (t == 0) {
    float B0 = sv[0];
    float wth = expf(lmaxp[0] + 1e-3f - B0);
    float omu = -expm1f(-wth);
    float delta = 8388608.0f * omu;
    uint32_t thr;
    if (delta >= 8388592.0f) thr = 0u;
    else {
      thr = 8388608u - (uint32_t)delta;
      thr = (thr > 24u) ? (thr - 24u) : 0u;
    }
    sthr = thr;
  }
  __syncthreads();
  uint32_t thr = sthr;

  for (int c = 256 + t; c < KP; c += 256) {
    uint32_t o0, o1;
    threefry2x32(0u, base | (uint32_t)c, o0, o1);
    uint32_t bits = o0 ^ o1;
    if ((bits >> 9) >= thr) {
      float g = gumbel_from_bits(bits) + logits[c];
      if (g > best) { best = g; bi = c; }
    }
  }
  sv[t] = best; si[t] = bi; __syncthreads();
  for (int o = 128; o; o >>= 1) {
    if (t < o) {
      if (sv[t + o] > sv[t] || (sv[t + o] == sv[t] && si[t + o] < si[t])) {
        sv[t] = sv[t + o]; si[t] = si[t + o];
      }
    }
    __syncthreads();
  }
  if (t == 0) idx[r] = si[0];
}

// ---------------- resample weights + final p1 ------------------------------
__global__ __launch_bounds__(1024) void resample_kernel(
    const float* __restrict__ p1v, const int* __restrict__ idx,
    float* __restrict__ pn, float* __restrict__ p1out, float* __restrict__ wexp) {
  __shared__ float red[1024];
  int t = threadIdx.x;
  float m = -INFINITY;
  for (int k = t; k < KP; k += 1024) {
    float pv = p1v[idx[k]];
    float w = expf(pv);
    float v = logf(w / (0.5f * w + (0.5f / KP)));
    pn[k] = v;
    m = fmaxf(m, v);
  }
  red[t] = m; __syncthreads();
  for (int o = 512; o; o >>= 1) { if (t < o) red[t] = fmaxf(red[t], red[t + o]); __syncthreads(); }
  m = red[0]; __syncthreads();
  float sum = 0.0f;
  for (int k = t; k < KP; k += 1024) sum += expf(pn[k] - m);
  red[t] = sum; __syncthreads();
  for (int o = 512; o; o >>= 1) { if (t < o) red[t] += red[t + o]; __syncthreads(); }
  float lse = m + logf(red[0]);
  for (int k = t; k < KP; k += 1024) {
    float v = pn[k] - lse;
    p1out[k] = v;
    wexp[k] = expf(v);
  }
}

// ---------------- gather h1 + per-block partial weighted sums --------------
__global__ __launch_bounds__(256) void gather_kernel(
    const float* __restrict__ h1pre, const int* __restrict__ idx,
    const float* __restrict__ wexp, float* __restrict__ h1out,
    float* __restrict__ partials) {
  int t = threadIdx.x;
  int k0 = blockIdx.x * 64;
  float part[4] = {0.f, 0.f, 0.f, 0.f};
  for (int kk = 0; kk < 64; ++kk) {
    int k = k0 + kk;
    int src = idx[k];
    float w = wexp[k];
#pragma unroll
    for (int c = 0; c < 4; ++c) {
      float v = h1pre[(size_t)src * HD + t + c * 256];
      h1out[(size_t)k * HD + t + c * 256] = v;
      part[c] = fmaf(w, v, part[c]);
    }
  }
#pragma unroll
  for (int c = 0; c < 4; ++c) partials[(size_t)blockIdx.x * HD + t + c * 256] = part[c];
}

__global__ __launch_bounds__(256) void reduce_mean_kernel(
    const float* __restrict__ partials, float* __restrict__ mean_hid) {
  int j = blockIdx.x * 256 + threadIdx.x;
  float s = 0.0f;
  for (int b = 0; b < 256; ++b) s += partials[(size_t)b * HD + j];
  mean_hid[j] = s;
}

// ---------------- final 2-layer head ---------------------------------------
__global__ __launch_bounds__(64) void final_kernel(
    const float* __restrict__ mean_hid,
    const float* __restrict__ wh1, const float* __restrict__ bh1,
    const float* __restrict__ wh2, const float* __restrict__ bh2,
    float* __restrict__ out) {
  __shared__ float hrelu[24];
  int t = threadIdx.x;
  if (t < 24) {
    float s = bh1[t];
    for (int i = 0; i < HD; ++i) s = fmaf(mean_hid[i], wh1[i * 24 + t], s);
    hrelu[t] = fmaxf(s, 0.0f);
  }
  __syncthreads();
  if (t < 2) {
    float s = bh2[t];
    for (int j = 0; j < 24; ++j) s = fmaf(hrelu[j], wh2[j * 2 + t], s);
    out[t] = s;
  }
}

extern "C" void kernel_launch(void* const* d_in, const int* in_sizes, int n_in,
                              void* d_out, int out_size, void* d_ws, size_t ws_size,
                              hipStream_t stream) {
  (void)in_sizes; (void)n_in; (void)out_size; (void)ws_size;
  const float* input_ = (const float*)d_in[0];
  const float* h0    = (const float*)d_in[1];
  const float* p0    = (const float*)d_in[2];
  const float* eps   = (const float*)d_in[3];
  const float* w_z   = (const float*)d_in[4];
  const float* b_z   = (const float*)d_in[5];
  const float* w_r   = (const float*)d_in[6];
  const float* b_r   = (const float*)d_in[7];
  const float* w_n   = (const float*)d_in[8];
  const float* b_n   = (const float*)d_in[9];
  const float* w_obs = (const float*)d_in[10];
  const float* b_obs = (const float*)d_in[11];
  const float* w_h1  = (const float*)d_in[12];
  const float* b_h1  = (const float*)d_in[13];
  const float* w_h2  = (const float*)d_in[14];
  const float* b_h2  = (const float*)d_in[15];

  float* out = (float*)d_out;
  float* out_loc = out;                       // 2
  float* out_h1  = out + 2;                   // KP*HD (z scratch, then final h1)
  float* out_p1  = out + 2 + (size_t)KP * HD; // KP

  float* ws = (float*)d_ws;
  float* rh      = ws;                          // KP*HD
  float* h1pre   = ws + (size_t)KP * HD;        // KP*HD
  float* zb      = ws + 2 * (size_t)KP * HD;    // 1024
  float* rb      = zb + 1024;                   // 1024
  float* nb      = rb + 1024;                   // 2048
  float* ob      = nb + 2048;                   // [0]=obs bias, [8]=Lmax
  float* sbuf    = ob + 16;                     // KP
  float* p1v     = sbuf + KP;                   // KP
  float* logits  = p1v + KP;                    // KP
  float* pn      = logits + KP;                 // KP
  float* wexpb   = pn + KP;                     // KP
  float* mean_hid= wexpb + KP;                  // 1024
  float* partials= mean_hid + 1024;             // 256*1024
  int*   idxb    = (int*)(partials + 256 * HD); // KP ints
  _Float16* wt   = (_Float16*)(partials + 256 * HD + KP); // 8M halfs
  _Float16* wzHi = wt;
  _Float16* wzLo = wt + 1 * (size_t)HD * HD;
  _Float16* wrHi = wt + 2 * (size_t)HD * HD;
  _Float16* wrLo = wt + 3 * (size_t)HD * HD;
  _Float16* wmHi = wt + 4 * (size_t)HD * HD;
  _Float16* wmLo = wt + 5 * (size_t)HD * HD;
  _Float16* wvHi = wt + 6 * (size_t)HD * HD;
  _Float16* wvLo = wt + 7 * (size_t)HD * HD;

  bias_kernel<<<17, 256, 0, stream>>>(input_, w_z, b_z, w_r, b_r, w_n, b_n,
                                      w_obs, b_obs, zb, rb, nb, ob);

  dim3 gs(32, 32, 4);
  splitw_kernel<<<gs, 256, 0, stream>>>(w_z, w_r, w_n, wzHi, wzLo, wrHi, wrLo,
                                        wmHi, wmLo, wvHi, wvLo);

  dim3 g1(KP / 128, HD / 64);
  gemm_zr_mfma<<<g1, 256, 0, stream>>>(h0, wzHi, wzLo, wrHi, wrLo, zb, rb,
                                       out_h1 /*z*/, rh);

  gemm_n_mfma<<<g1, 256, 0, stream>>>(rh, wmHi, wmLo, wvHi, wvLo, nb,
                                      h0, eps, out_h1 /*z*/, h1pre);

  score_kernel<<<KP / 4, 256, 0, stream>>>(h1pre, w_obs, ob, p0, sbuf);

  softmax_kernel<<<1, 1024, 0, stream>>>(sbuf, p1v, logits, ob + 8);

  categorical_kernel<<<KP, 256, 0, stream>>>(logits, ob + 8, idxb);

  resample_kernel<<<1, 1024, 0, stream>>>(p1v, idxb, pn, out_p1, wexpb);

  gather_kernel<<<KP / 64, 256, 0, stream>>>(h1pre, idxb, wexpb, out_h1, partials);

  reduce_mean_kernel<<<4, 256, 0, stream>>>(partials, mean_hid);

  final_kernel<<<1, 64, 0, stream>>>(mean_hid, w_h1, b_h1, w_h2, b_h2, out_loc);
}

// Round 5
// 1241.204 us; speedup vs baseline: 2.1473x; 1.0490x over previous
//
#include <hip/hip_runtime.h>
#include <math.h>
#include <stdint.h>

#define KP 16384
#define IN_DIM 512
#define HD 1024

typedef _Float16 f16x8 __attribute__((ext_vector_type(8)));
typedef float f32x4 __attribute__((ext_vector_type(4)));

// ---------------- threefry2x32 (JAX key(42) => k0=0, k1=42) ----------------
__device__ __forceinline__ uint32_t rotl(uint32_t x, uint32_t r) {
  // funnel-shift: (x:x) >> (32-r) == rotl(x, r); single v_alignbit_b32
  return __builtin_amdgcn_alignbit(x, x, 32u - r);
}

__device__ __forceinline__ void threefry2x32(uint32_t x0, uint32_t x1,
                                             uint32_t& o0, uint32_t& o1) {
  const uint32_t ks0 = 0u, ks1 = 42u, ks2 = 0u ^ 42u ^ 0x1BD11BDAu;
  x0 += ks0; x1 += ks1;
#define TF_R4(r0, r1, r2, r3) \
  x0 += x1; x1 = rotl(x1, r0); x1 ^= x0; \
  x0 += x1; x1 = rotl(x1, r1); x1 ^= x0; \
  x0 += x1; x1 = rotl(x1, r2); x1 ^= x0; \
  x0 += x1; x1 = rotl(x1, r3); x1 ^= x0;
  TF_R4(13u,15u,26u,6u);   x0 += ks1; x1 += ks2 + 1u;
  TF_R4(17u,29u,16u,24u);  x0 += ks2; x1 += ks0 + 2u;
  TF_R4(13u,15u,26u,6u);   x0 += ks0; x1 += ks1 + 3u;
  TF_R4(17u,29u,16u,24u);  x0 += ks1; x1 += ks2 + 4u;
  TF_R4(13u,15u,26u,6u);   x0 += ks2; x1 += ks0 + 5u;
#undef TF_R4
  o0 = x0; o1 = x1;
}

__device__ __forceinline__ float gumbel_from_bits(uint32_t b) {
  uint32_t ub = (b >> 9) | 0x3f800000u;
  float u = __uint_as_float(ub) - 1.0f;
  u = fmaxf(u, 1.1754943508222875e-38f);
  return -logf(-logf(u));
}

// ---------------- bias precompute: input_ @ W[1024:,:] + b ----------------
__global__ __launch_bounds__(256) void bias_kernel(
    const float* __restrict__ in,
    const float* __restrict__ wz, const float* __restrict__ bz,
    const float* __restrict__ wr, const float* __restrict__ br,
    const float* __restrict__ wn, const float* __restrict__ bn,
    const float* __restrict__ wobs, const float* __restrict__ bobs,
    float* __restrict__ zb, float* __restrict__ rb,
    float* __restrict__ nb, float* __restrict__ ob) {
  __shared__ float sin_[IN_DIM];
  int t = threadIdx.x;
  for (int i = t; i < IN_DIM; i += 256) sin_[i] = in[i];
  __syncthreads();
  int gid = blockIdx.x * 256 + t;
  if (gid < 1024) {
    float s = bz[gid];
    for (int i = 0; i < IN_DIM; ++i) s = fmaf(sin_[i], wz[(HD + i) * HD + gid], s);
    zb[gid] = s;
  } else if (gid < 2048) {
    int j = gid - 1024;
    float s = br[j];
    for (int i = 0; i < IN_DIM; ++i) s = fmaf(sin_[i], wr[(HD + i) * HD + j], s);
    rb[j] = s;
  } else if (gid < 4096) {
    int j = gid - 2048;
    float s = bn[j];
    for (int i = 0; i < IN_DIM; ++i) s = fmaf(sin_[i], wn[(HD + i) * 2048 + j], s);
    nb[j] = s;
  } else if (gid == 4096) {
    float s = bobs[0];
    for (int i = 0; i < IN_DIM; ++i) s = fmaf(sin_[i], wobs[HD + i], s);
    ob[0] = s;
  }
}

// ---------------- weight transpose + fp16 2-term split (x64 prescale) ------
__global__ __launch_bounds__(256) void splitw_kernel(
    const float* __restrict__ wz, const float* __restrict__ wr,
    const float* __restrict__ wn,
    _Float16* __restrict__ zHi, _Float16* __restrict__ zLo,
    _Float16* __restrict__ rHi, _Float16* __restrict__ rLo,
    _Float16* __restrict__ mHi, _Float16* __restrict__ mLo,
    _Float16* __restrict__ vHi, _Float16* __restrict__ vLo) {
  __shared__ float tile[32][33];
  int m = blockIdx.z;
  const float* src; int ld, cofs; _Float16 *oh, *ol;
  if (m == 0)      { src = wz; ld = 1024; cofs = 0;    oh = zHi; ol = zLo; }
  else if (m == 1) { src = wr; ld = 1024; cofs = 0;    oh = rHi; ol = rLo; }
  else if (m == 2) { src = wn; ld = 2048; cofs = 0;    oh = mHi; ol = mLo; }
  else             { src = wn; ld = 2048; cofs = 1024; oh = vHi; ol = vLo; }
  int k0 = blockIdx.x * 32, n0 = blockIdx.y * 32;
  int tx = threadIdx.x & 31, ty = threadIdx.x >> 5;
#pragma unroll
  for (int i = 0; i < 4; ++i) {
    int k = ty * 4 + i;
    tile[k][tx] = src[(size_t)(k0 + k) * ld + cofs + n0 + tx];
  }
  __syncthreads();
#pragma unroll
  for (int i = 0; i < 4; ++i) {
    int n = ty * 4 + i;
    float v = tile[tx][n] * 64.0f;
    _Float16 h = (_Float16)v;
    _Float16 l = (_Float16)((v - (float)h) * 2048.0f);
    oh[(size_t)(n0 + n) * 1024 + k0 + tx] = h;
    ol[(size_t)(n0 + n) * 1024 + k0 + tx] = l;
  }
}

// ---------------- MFMA split-GEMM #1: z & rh ------------------------------
#define LDH 40   // halfs per LDS row (32 data + 8 pad); 80B, 16B-multiple

__global__ __launch_bounds__(256, 2) void gemm_zr_mfma(
    const float* __restrict__ A,  // h0: KP x HD fp32 (also epilogue h0)
    const _Float16* __restrict__ BzHi, const _Float16* __restrict__ BzLo,
    const _Float16* __restrict__ BrHi, const _Float16* __restrict__ BrLo,
    const float* __restrict__ zbias, const float* __restrict__ rbias,
    float* __restrict__ zout, float* __restrict__ rhout) {
  __shared__ __align__(16) _Float16 Ah[128 * LDH], Al[128 * LDH];
  __shared__ __align__(16) _Float16 B0h[64 * LDH], B0l[64 * LDH];
  __shared__ __align__(16) _Float16 B1h[64 * LDH], B1l[64 * LDH];
  int t = threadIdx.x;
  int row0 = blockIdx.x * 128, col0 = blockIdx.y * 64;
  int wave = t >> 6, lane = t & 63;
  int lr = lane & 15, hh = lane >> 4;
  int WR = (wave >> 1) * 64, WC = (wave & 1) * 32;

  f32x4 acc0[4][2][2] = {};
  f32x4 acc1[4][2][2] = {};

  for (int kb = 0; kb < 1024; kb += 32) {
#pragma unroll
    for (int p = 0; p < 2; ++p) {
      int id = t + p * 256;
      int row = id >> 2, kc = id & 3;
      const float* g = &A[(size_t)(row0 + row) * 1024 + kb + kc * 8];
      float4 v0 = *(const float4*)g;
      float4 v1 = *(const float4*)(g + 4);
      float vv[8] = {v0.x, v0.y, v0.z, v0.w, v1.x, v1.y, v1.z, v1.w};
      f16x8 hi, lo;
#pragma unroll
      for (int j = 0; j < 8; ++j) {
        _Float16 h = (_Float16)vv[j];
        hi[j] = h;
        lo[j] = (_Float16)((vv[j] - (float)h) * 2048.0f);
      }
      *(f16x8*)&Ah[row * LDH + kc * 8] = hi;
      *(f16x8*)&Al[row * LDH + kc * 8] = lo;
    }
    {
      int n = t >> 2, kc = t & 3;
      size_t gofs = (size_t)(col0 + n) * 1024 + kb + kc * 8;
      int lofs = n * LDH + kc * 8;
      *(f16x8*)&B0h[lofs] = *(const f16x8*)&BzHi[gofs];
      *(f16x8*)&B0l[lofs] = *(const f16x8*)&BzLo[gofs];
      *(f16x8*)&B1h[lofs] = *(const f16x8*)&BrHi[gofs];
      *(f16x8*)&B1l[lofs] = *(const f16x8*)&BrLo[gofs];
    }
    __syncthreads();
    f16x8 ah[4], al[4], bh[2][2], bl[2][2];
#pragma unroll
    for (int mt = 0; mt < 4; ++mt) {
      int r = WR + mt * 16 + lr;
      ah[mt] = *(f16x8*)&Ah[r * LDH + hh * 8];
      al[mt] = *(f16x8*)&Al[r * LDH + hh * 8];
    }
#pragma unroll
    for (int nt = 0; nt < 2; ++nt) {
      int c = WC + nt * 16 + lr;
      bh[0][nt] = *(f16x8*)&B0h[c * LDH + hh * 8];
      bl[0][nt] = *(f16x8*)&B0l[c * LDH + hh * 8];
      bh[1][nt] = *(f16x8*)&B1h[c * LDH + hh * 8];
      bl[1][nt] = *(f16x8*)&B1l[c * LDH + hh * 8];
    }
#pragma unroll
    for (int mt = 0; mt < 4; ++mt)
#pragma unroll
      for (int nt = 0; nt < 2; ++nt)
#pragma unroll
        for (int m = 0; m < 2; ++m) {
          acc0[mt][nt][m] = __builtin_amdgcn_mfma_f32_16x16x32_f16(ah[mt], bh[m][nt], acc0[mt][nt][m], 0, 0, 0);
          acc1[mt][nt][m] = __builtin_amdgcn_mfma_f32_16x16x32_f16(ah[mt], bl[m][nt], acc1[mt][nt][m], 0, 0, 0);
          acc1[mt][nt][m] = __builtin_amdgcn_mfma_f32_16x16x32_f16(al[mt], bh[m][nt], acc1[mt][nt][m], 0, 0, 0);
        }
    __syncthreads();
  }
  const float INV = 1.0f / 2048.0f, WS = 1.0f / 64.0f;
#pragma unroll
  for (int mt = 0; mt < 4; ++mt)
#pragma unroll
    for (int nt = 0; nt < 2; ++nt) {
      int col = col0 + WC + nt * 16 + lr;
#pragma unroll
      for (int q = 0; q < 4; ++q) {
        int row = row0 + WR + mt * 16 + hh * 4 + q;
        float vz = (acc0[mt][nt][0][q] + acc1[mt][nt][0][q] * INV) * WS + zbias[col];
        float vr = (acc0[mt][nt][1][q] + acc1[mt][nt][1][q] * INV) * WS + rbias[col];
        float z = 1.0f / (1.0f + expf(-vz));
        float r = 1.0f / (1.0f + expf(-vr));
        float hv = A[(size_t)row * 1024 + col];
        zout[(size_t)row * 1024 + col] = z;
        rhout[(size_t)row * 1024 + col] = r * hv;
      }
    }
}

// ---------------- MFMA split-GEMM #2: n_pre (mu,var) + h1 epilogue ---------
__global__ __launch_bounds__(256, 2) void gemm_n_mfma(
    const float* __restrict__ A,  // rh: KP x HD fp32
    const _Float16* __restrict__ BmHi, const _Float16* __restrict__ BmLo,
    const _Float16* __restrict__ BvHi, const _Float16* __restrict__ BvLo,
    const float* __restrict__ nbias,
    const float* __restrict__ h0, const float* __restrict__ eps,
    const float* __restrict__ zbuf, float* __restrict__ h1out) {
  __shared__ __align__(16) _Float16 Ah[128 * LDH], Al[128 * LDH];
  __shared__ __align__(16) _Float16 B0h[64 * LDH], B0l[64 * LDH];
  __shared__ __align__(16) _Float16 B1h[64 * LDH], B1l[64 * LDH];
  int t = threadIdx.x;
  int row0 = blockIdx.x * 128, col0 = blockIdx.y * 64;
  int wave = t >> 6, lane = t & 63;
  int lr = lane & 15, hh = lane >> 4;
  int WR = (wave >> 1) * 64, WC = (wave & 1) * 32;

  f32x4 acc0[4][2][2] = {};
  f32x4 acc1[4][2][2] = {};

  for (int kb = 0; kb < 1024; kb += 32) {
#pragma unroll
    for (int p = 0; p < 2; ++p) {
      int id = t + p * 256;
      int row = id >> 2, kc = id & 3;
      const float* g = &A[(size_t)(row0 + row) * 1024 + kb + kc * 8];
      float4 v0 = *(const float4*)g;
      float4 v1 = *(const float4*)(g + 4);
      float vv[8] = {v0.x, v0.y, v0.z, v0.w, v1.x, v1.y, v1.z, v1.w};
      f16x8 hi, lo;
#pragma unroll
      for (int j = 0; j < 8; ++j) {
        _Float16 h = (_Float16)vv[j];
        hi[j] = h;
        lo[j] = (_Float16)((vv[j] - (float)h) * 2048.0f);
      }
      *(f16x8*)&Ah[row * LDH + kc * 8] = hi;
      *(f16x8*)&Al[row * LDH + kc * 8] = lo;
    }
    {
      int n = t >> 2, kc = t & 3;
      size_t gofs = (size_t)(col0 + n) * 1024 + kb + kc * 8;
      int lofs = n * LDH + kc * 8;
      *(f16x8*)&B0h[lofs] = *(const f16x8*)&BmHi[gofs];
      *(f16x8*)&B0l[lofs] = *(const f16x8*)&BmLo[gofs];
      *(f16x8*)&B1h[lofs] = *(const f16x8*)&BvHi[gofs];
      *(f16x8*)&B1l[lofs] = *(const f16x8*)&BvLo[gofs];
    }
    __syncthreads();
    f16x8 ah[4], al[4], bh[2][2], bl[2][2];
#pragma unroll
    for (int mt = 0; mt < 4; ++mt) {
      int r = WR + mt * 16 + lr;
      ah[mt] = *(f16x8*)&Ah[r * LDH + hh * 8];
      al[mt] = *(f16x8*)&Al[r * LDH + hh * 8];
    }
#pragma unroll
    for (int nt = 0; nt < 2; ++nt) {
      int c = WC + nt * 16 + lr;
      bh[0][nt] = *(f16x8*)&B0h[c * LDH + hh * 8];
      bl[0][nt] = *(f16x8*)&B0l[c * LDH + hh * 8];
      bh[1][nt] = *(f16x8*)&B1h[c * LDH + hh * 8];
      bl[1][nt] = *(f16x8*)&B1l[c * LDH + hh * 8];
    }
#pragma unroll
    for (int mt = 0; mt < 4; ++mt)
#pragma unroll
      for (int nt = 0; nt < 2; ++nt)
#pragma unroll
        for (int m = 0; m < 2; ++m) {
          acc0[mt][nt][m] = __builtin_amdgcn_mfma_f32_16x16x32_f16(ah[mt], bh[m][nt], acc0[mt][nt][m], 0, 0, 0);
          acc1[mt][nt][m] = __builtin_amdgcn_mfma_f32_16x16x32_f16(ah[mt], bl[m][nt], acc1[mt][nt][m], 0, 0, 0);
          acc1[mt][nt][m] = __builtin_amdgcn_mfma_f32_16x16x32_f16(al[mt], bh[m][nt], acc1[mt][nt][m], 0, 0, 0);
        }
    __syncthreads();
  }
  const float INV = 1.0f / 2048.0f, WS = 1.0f / 64.0f;
#pragma unroll
  for (int mt = 0; mt < 4; ++mt)
#pragma unroll
    for (int nt = 0; nt < 2; ++nt) {
      int col = col0 + WC + nt * 16 + lr;
#pragma unroll
      for (int q = 0; q < 4; ++q) {
        int row = row0 + WR + mt * 16 + hh * 4 + q;
        size_t off = (size_t)row * 1024 + col;
        float mu = (acc0[mt][nt][0][q] + acc1[mt][nt][0][q] * INV) * WS + nbias[col];
        float var = (acc0[mt][nt][1][q] + acc1[mt][nt][1][q] * INV) * WS + nbias[1024 + col];
        float sp = fmaxf(var, 0.0f) + log1pf(expf(-fabsf(var)));
        float n = tanhf(mu + eps[off] * sp);
        float z = zbuf[off];
        h1out[off] = (1.0f - z) * n + z * h0[off];
      }
    }
}

// ---------------- score: s = h1@wobs[:1024] + ob + p0 ----------------------
__global__ __launch_bounds__(256) void score_kernel(
    const float* __restrict__ h1, const float* __restrict__ wobs,
    const float* __restrict__ ob, const float* __restrict__ p0,
    float* __restrict__ s) {
  __shared__ float w[HD];
  int t = threadIdx.x;
  for (int i = t; i < HD; i += 256) w[i] = wobs[i];
  __syncthreads();
  int wave = t >> 6, lane = t & 63;
  int row = blockIdx.x * 4 + wave;
  float acc = 0.0f;
  for (int c = lane * 4; c < HD; c += 256) {
    float4 v = *(const float4*)&h1[(size_t)row * HD + c];
    acc = fmaf(v.x, w[c], acc);
    acc = fmaf(v.y, w[c + 1], acc);
    acc = fmaf(v.z, w[c + 2], acc);
    acc = fmaf(v.w, w[c + 3], acc);
  }
#pragma unroll
  for (int off = 32; off; off >>= 1) acc += __shfl_down(acc, off);
  if (lane == 0) s[row] = acc + ob[0] + p0[row];
}

// ---------------- log_softmax over K + categorical logits + Lmax -----------
__global__ __launch_bounds__(1024) void softmax_kernel(
    const float* __restrict__ s, float* __restrict__ p1v,
    float* __restrict__ logits, float* __restrict__ lmaxp) {
  __shared__ float red[1024];
  int t = threadIdx.x;
  float m = -INFINITY;
  for (int k = t; k < KP; k += 1024) m = fmaxf(m, s[k]);
  red[t] = m; __syncthreads();
  for (int o = 512; o; o >>= 1) { if (t < o) red[t] = fmaxf(red[t], red[t + o]); __syncthreads(); }
  m = red[0]; __syncthreads();
  float sum = 0.0f;
  for (int k = t; k < KP; k += 1024) sum += expf(s[k] - m);
  red[t] = sum; __syncthreads();
  for (int o = 512; o; o >>= 1) { if (t < o) red[t] += red[t + o]; __syncthreads(); }
  float ls = logf(red[0]);
  for (int k = t; k < KP; k += 1024) {
    float p = s[k] - m - ls;
    p1v[k] = p;
    logits[k] = logf(0.5f * expf(p) + (0.5f / KP));
  }
  if (t == 0) lmaxp[0] = logf(0.5f * expf(-ls) + (0.5f / KP));
}

// ---------------- categorical: integer-only scan + LDS survivor queue ------
#define MAXS 2048

__global__ __launch_bounds__(256) void categorical_kernel(
    const float* __restrict__ logits, const float* __restrict__ lmaxp,
    int* __restrict__ idx) {
  __shared__ float sv[256];
  __shared__ int si[256];
  __shared__ uint32_t s_bits[MAXS];
  __shared__ int s_c[MAXS];
  __shared__ int s_cnt;
  __shared__ uint32_t sthr;
  int r = blockIdx.x;
  int t = threadIdx.x;
  uint32_t base = (uint32_t)r << 14;

  // sample phase: element c = t (exact evaluation)
  float best; int bi;
  {
    uint32_t o0, o1;
    threefry2x32(0u, base | (uint32_t)t, o0, o1);
    best = gumbel_from_bits(o0 ^ o1) + logits[t];
    bi = t;
  }
  sv[t] = best; __syncthreads();
  for (int o = 128; o; o >>= 1) { if (t < o) sv[t] = fmaxf(sv[t], sv[t + o]); __syncthreads(); }
  if (t == 0) {
    float B0 = sv[0];
    float wth = expf(lmaxp[0] + 1e-3f - B0);
    float omu = -expm1f(-wth);
    float delta = 8388608.0f * omu;
    uint32_t thr;
    if (delta >= 8388592.0f) thr = 0u;
    else {
      thr = 8388608u - (uint32_t)delta;
      thr = (thr > 24u) ? (thr - 24u) : 0u;
    }
    sthr = thr;
    s_cnt = 0;
  }
  __syncthreads();
  uint32_t thr = sthr;

  // scan: pure integer threefry + compare; survivors queued to LDS
#pragma unroll 3
  for (int c = 256 + t; c < KP; c += 256) {
    uint32_t o0, o1;
    threefry2x32(0u, base | (uint32_t)c, o0, o1);
    uint32_t bits = o0 ^ o1;
    if ((bits >> 9) >= thr) {
      int slot = atomicAdd(&s_cnt, 1);
      if (slot < MAXS) {
        s_bits[slot] = bits;
        s_c[slot] = c;
      } else {
        // overflow fallback: evaluate inline (order-independent w.r.t. result)
        float g = gumbel_from_bits(bits) + logits[c];
        if (g > best || (g == best && c < bi)) { best = g; bi = c; }
      }
    }
  }
  __syncthreads();

  // survivor phase
  int n = s_cnt < MAXS ? s_cnt : MAXS;
  for (int i = t; i < n; i += 256) {
    int c = s_c[i];
    float g = gumbel_from_bits(s_bits[i]) + logits[c];
    if (g > best || (g == best && c < bi)) { best = g; bi = c; }
  }

  sv[t] = best; si[t] = bi; __syncthreads();
  for (int o = 128; o; o >>= 1) {
    if (t < o) {
      if (sv[t + o] > sv[t] || (sv[t + o] == sv[t] && si[t + o] < si[t])) {
        sv[t] = sv[t + o]; si[t] = si[t + o];
      }
    }
    __syncthreads();
  }
  if (t == 0) idx[r] = si[0];
}

// ---------------- resample weights + final p1 ------------------------------
__global__ __launch_bounds__(1024) void resample_kernel(
    const float* __restrict__ p1v, const int* __restrict__ idx,
    float* __restrict__ pn, float* __restrict__ p1out, float* __restrict__ wexp) {
  __shared__ float red[1024];
  int t = threadIdx.x;
  float m = -INFINITY;
  for (int k = t; k < KP; k += 1024) {
    float pv = p1v[idx[k]];
    float w = expf(pv);
    float v = logf(w / (0.5f * w + (0.5f / KP)));
    pn[k] = v;
    m = fmaxf(m, v);
  }
  red[t] = m; __syncthreads();
  for (int o = 512; o; o >>= 1) { if (t < o) red[t] = fmaxf(red[t], red[t + o]); __syncthreads(); }
  m = red[0]; __syncthreads();
  float sum = 0.0f;
  for (int k = t; k < KP; k += 1024) sum += expf(pn[k] - m);
  red[t] = sum; __syncthreads();
  for (int o = 512; o; o >>= 1) { if (t < o) red[t] += red[t + o]; __syncthreads(); }
  float lse = m + logf(red[0]);
  for (int k = t; k < KP; k += 1024) {
    float v = pn[k] - lse;
    p1out[k] = v;
    wexp[k] = expf(v);
  }
}

// ---------------- gather h1 + per-block partial weighted sums --------------
__global__ __launch_bounds__(256) void gather_kernel(
    const float* __restrict__ h1pre, const int* __restrict__ idx,
    const float* __restrict__ wexp, float* __restrict__ h1out,
    float* __restrict__ partials) {
  int t = threadIdx.x;
  int k0 = blockIdx.x * 64;
  float part[4] = {0.f, 0.f, 0.f, 0.f};
  for (int kk = 0; kk < 64; ++kk) {
    int k = k0 + kk;
    int src = idx[k];
    float w = wexp[k];
#pragma unroll
    for (int c = 0; c < 4; ++c) {
      float v = h1pre[(size_t)src * HD + t + c * 256];
      h1out[(size_t)k * HD + t + c * 256] = v;
      part[c] = fmaf(w, v, part[c]);
    }
  }
#pragma unroll
  for (int c = 0; c < 4; ++c) partials[(size_t)blockIdx.x * HD + t + c * 256] = part[c];
}

__global__ __launch_bounds__(256) void reduce_mean_kernel(
    const float* __restrict__ partials, float* __restrict__ mean_hid) {
  int j = blockIdx.x * 256 + threadIdx.x;
  float s = 0.0f;
  for (int b = 0; b < 256; ++b) s += partials[(size_t)b * HD + j];
  mean_hid[j] = s;
}

// ---------------- final 2-layer head ---------------------------------------
__global__ __launch_bounds__(64) void final_kernel(
    const float* __restrict__ mean_hid,
    const float* __restrict__ wh1, const float* __restrict__ bh1,
    const float* __restrict__ wh2, const float* __restrict__ bh2,
    float* __restrict__ out) {
  __shared__ float hrelu[24];
  int t = threadIdx.x;
  if (t < 24) {
    float s = bh1[t];
    for (int i = 0; i < HD; ++i) s = fmaf(mean_hid[i], wh1[i * 24 + t], s);
    hrelu[t] = fmaxf(s, 0.0f);
  }
  __syncthreads();
  if (t < 2) {
    float s = bh2[t];
    for (int j = 0; j < 24; ++j) s = fmaf(hrelu[j], wh2[j * 2 + t], s);
    out[t] = s;
  }
}

extern "C" void kernel_launch(void* const* d_in, const int* in_sizes, int n_in,
                              void* d_out, int out_size, void* d_ws, size_t ws_size,
                              hipStream_t stream) {
  (void)in_sizes; (void)n_in; (void)out_size; (void)ws_size;
  const float* input_ = (const float*)d_in[0];
  const float* h0    = (const float*)d_in[1];
  const float* p0    = (const float*)d_in[2];
  const float* eps   = (const float*)d_in[3];
  const float* w_z   = (const float*)d_in[4];
  const float* b_z   = (const float*)d_in[5];
  const float* w_r   = (const float*)d_in[6];
  const float* b_r   = (const float*)d_in[7];
  const float* w_n   = (const float*)d_in[8];
  const float* b_n   = (const float*)d_in[9];
  const float* w_obs = (const float*)d_in[10];
  const float* b_obs = (const float*)d_in[11];
  const float* w_h1  = (const float*)d_in[12];
  const float* b_h1  = (const float*)d_in[13];
  const float* w_h2  = (const float*)d_in[14];
  const float* b_h2  = (const float*)d_in[15];

  float* out = (float*)d_out;
  float* out_loc = out;                       // 2
  float* out_h1  = out + 2;                   // KP*HD (z scratch, then final h1)
  float* out_p1  = out + 2 + (size_t)KP * HD; // KP

  float* ws = (float*)d_ws;
  float* rh      = ws;                          // KP*HD
  float* h1pre   = ws + (size_t)KP * HD;        // KP*HD
  float* zb      = ws + 2 * (size_t)KP * HD;    // 1024
  float* rb      = zb + 1024;                   // 1024
  float* nb      = rb + 1024;                   // 2048
  float* ob      = nb + 2048;                   // [0]=obs bias, [8]=Lmax
  float* sbuf    = ob + 16;                     // KP
  float* p1v     = sbuf + KP;                   // KP
  float* logits  = p1v + KP;                    // KP
  float* pn      = logits + KP;                 // KP
  float* wexpb   = pn + KP;                     // KP
  float* mean_hid= wexpb + KP;                  // 1024
  float* partials= mean_hid + 1024;             // 256*1024
  int*   idxb    = (int*)(partials + 256 * HD); // KP ints
  _Float16* wt   = (_Float16*)(partials + 256 * HD + KP); // 8M halfs
  _Float16* wzHi = wt;
  _Float16* wzLo = wt + 1 * (size_t)HD * HD;
  _Float16* wrHi = wt + 2 * (size_t)HD * HD;
  _Float16* wrLo = wt + 3 * (size_t)HD * HD;
  _Float16* wmHi = wt + 4 * (size_t)HD * HD;
  _Float16* wmLo = wt + 5 * (size_t)HD * HD;
  _Float16* wvHi = wt + 6 * (size_t)HD * HD;
  _Float16* wvLo = wt + 7 * (size_t)HD * HD;

  bias_kernel<<<17, 256, 0, stream>>>(input_, w_z, b_z, w_r, b_r, w_n, b_n,
                                      w_obs, b_obs, zb, rb, nb, ob);

  dim3 gs(32, 32, 4);
  splitw_kernel<<<gs, 256, 0, stream>>>(w_z, w_r, w_n, wzHi, wzLo, wrHi, wrLo,
                                        wmHi, wmLo, wvHi, wvLo);

  dim3 g1(KP / 128, HD / 64);
  gemm_zr_mfma<<<g1, 256, 0, stream>>>(h0, wzHi, wzLo, wrHi, wrLo, zb, rb,
                                       out_h1 /*z*/, rh);

  gemm_n_mfma<<<g1, 256, 0, stream>>>(rh, wmHi, wmLo, wvHi, wvLo, nb,
                                      h0, eps, out_h1 /*z*/, h1pre);

  score_kernel<<<KP / 4, 256, 0, stream>>>(h1pre, w_obs, ob, p0, sbuf);

  softmax_kernel<<<1, 1024, 0, stream>>>(sbuf, p1v, logits, ob + 8);

  categorical_kernel<<<KP, 256, 0, stream>>>(logits, ob + 8, idxb);

  resample_kernel<<<1, 1024, 0, stream>>>(p1v, idxb, pn, out_p1, wexpb);

  gather_kernel<<<KP / 64, 256, 0, stream>>>(h1pre, idxb, wexpb, out_h1, partials);

  reduce_mean_kernel<<<4, 256, 0, stream>>>(partials, mean_hid);

  final_kernel<<<1, 64, 0, stream>>>(mean_hid, w_h1, b_h1, w_h2, b_h2, out_loc);
}